// Round 13
// baseline (263.635 us; speedup 1.0000x reference)
//
#include <hip/hip_runtime.h>

// SelfAttention: out = softmax((xWq)(xWk)^T/32) @ (xWv), f32, S=4096, D=1024.
// R13: deferred per-tile softmax fused into k_qkt epilogue. k_qkt writes
// Pt = exp(s - m_tile) f16 + per-(row,tile) {mtile, tsum}; k_scale builds
// scale[row][tile] = e^{mtile-m}/sum; k_rescale applies it -> P. Softmax
// kernel (96MB traffic) deleted; k_qkt S-write halves (64->32MB).
// scores = 8rr^T + (pr^T+rq^T)/64 + (x·(Mres/32))·x^T.
// ws (MiB): xh 0, xl 8 (r/p/q overlay), Th 16, Tl 24, Vt 32, Pt 40..72,
//   mtile 72, tsum 73, scale 74; P 0..32 after k_rescale;
//   temps in dead-Pt region: Wqh 40.., Mth 48, Wtvh 52, sa/sb 54.

typedef _Float16 f16;
typedef f16 f16x8 __attribute__((ext_vector_type(8)));
typedef f16 f16x4v __attribute__((ext_vector_type(4)));
typedef float f32x4 __attribute__((ext_vector_type(4)));
typedef float f32x16 __attribute__((ext_vector_type(16)));
typedef unsigned short u16;
typedef u16 u16x8 __attribute__((ext_vector_type(8)));

extern __shared__ char dsm[];  // single dynamic-LDS symbol for the whole TU

__device__ __forceinline__ void split_f32(float v, f16& h, f16& l) {
  h = (f16)v;
  l = (f16)(v - (float)h);
}

__device__ __forceinline__ void gload16(const void* g, void* l) {
  __builtin_amdgcn_global_load_lds(
      (const __attribute__((address_space(1))) void*)g,
      (__attribute__((address_space(3))) void*)l, 16, 0, 0);
}

// ---- prep: elementwise split f32 -> (h,l) f16 for x, Wq, Wk ----
__global__ __launch_bounds__(256) void k_split(
    const float* __restrict__ x, const float* __restrict__ wq,
    const float* __restrict__ wk, f16* __restrict__ xh, f16* __restrict__ xl,
    f16* __restrict__ qh, f16* __restrict__ ql, f16* __restrict__ kh,
    f16* __restrict__ kl) {
  const int z = blockIdx.z;
  const float* __restrict__ src = (z == 0) ? x : (z == 1) ? wq : wk;
  f16* __restrict__ oh = (z == 0) ? xh : (z == 1) ? qh : kh;
  f16* __restrict__ ol = (z == 0) ? xl : (z == 1) ? ql : kl;
  const int n4 = (z == 0) ? (4096 * 1024 / 4) : (1024 * 1024 / 4);
  for (int i = blockIdx.x * 256 + threadIdx.x; i < n4; i += 1024 * 256) {
    float4 f = ((const float4*)src)[i];
    f16x4v h, l;
    f16 hh, ll;
    split_f32(f.x, hh, ll); h[0] = hh; l[0] = ll;
    split_f32(f.y, hh, ll); h[1] = hh; l[1] = ll;
    split_f32(f.z, hh, ll); h[2] = hh; l[2] = ll;
    split_f32(f.w, hh, ll); h[3] = hh; l[3] = ll;
    ((f16x4v*)oh)[i] = h;
    ((f16x4v*)ol)[i] = l;
  }
}

// ---- prep: transpose+split-h Wv [a][d] f32 -> Wtvh [d][a] f16 ----
__global__ __launch_bounds__(256) void k_wsplit_v(const float* __restrict__ Wv,
                                                  f16* __restrict__ vt) {
  __shared__ float sh[64][65];
  const int kb = blockIdx.x * 64, nb = blockIdx.y * 64;
  const int t = threadIdx.x;
  const int r = t >> 2, c4 = (t & 3) * 16;
#pragma unroll
  for (int i = 0; i < 4; ++i) {
    float4 f = *(const float4*)&Wv[(size_t)(kb + r) * 1024 + nb + c4 + i * 4];
    sh[r][c4 + i * 4 + 0] = f.x;
    sh[r][c4 + i * 4 + 1] = f.y;
    sh[r][c4 + i * 4 + 2] = f.z;
    sh[r][c4 + i * 4 + 3] = f.w;
  }
  __syncthreads();
  const int n = t >> 2, ks = (t & 3) * 16;
  u16x8 h0, h1;
#pragma unroll
  for (int i = 0; i < 8; ++i) {
    h0[i] = __builtin_bit_cast(u16, (f16)sh[ks + i][n]);
    h1[i] = __builtin_bit_cast(u16, (f16)sh[ks + 8 + i][n]);
  }
  const size_t o = (size_t)(nb + n) * 1024 + kb + ks;
  *(u16x8*)&vt[o] = h0;
  *(u16x8*)&vt[o + 8] = h1;
}

// ---- prep: centered row sums ----
__global__ __launch_bounds__(256) void k_rowsums(const float* __restrict__ Wq,
                                                 const float* __restrict__ Wk,
                                                 float* __restrict__ sa,
                                                 float* __restrict__ sb) {
  const int z = blockIdx.y;
  const float* __restrict__ W = z ? Wk : Wq;
  float* __restrict__ o = z ? sb : sa;
  const int row = blockIdx.x * 4 + (threadIdx.x >> 6);
  const int lane = threadIdx.x & 63;
  const float4* src = (const float4*)(W + (size_t)row * 1024);
  float s = 0.f;
#pragma unroll
  for (int i = 0; i < 4; ++i) {
    float4 f = src[lane + 64 * i];
    s += f.x + f.y + f.z + f.w;
  }
#pragma unroll
  for (int off = 1; off < 64; off <<= 1) s += __shfl_xor(s, off, 64);
  if (lane == 0) o[row] = s - 512.0f;
}

// ---- prep: r = x*1, p = x*sa, q = x*sb ----
__global__ __launch_bounds__(256) void k_rpq(
    const float* __restrict__ x, const float* __restrict__ sa,
    const float* __restrict__ sb, float* __restrict__ rv,
    float* __restrict__ pv, float* __restrict__ qv) {
  const int row = blockIdx.x * 4 + (threadIdx.x >> 6);
  const int lane = threadIdx.x & 63;
  const float* xr = x + (size_t)row * 1024;
  float sr = 0.f, sp = 0.f, sq = 0.f;
#pragma unroll
  for (int i = 0; i < 4; ++i) {
    const int c = (lane + 64 * i) * 4;
    float4 f = *(const float4*)&xr[c];
    float4 a = *(const float4*)&sa[c];
    float4 b = *(const float4*)&sb[c];
    sr += f.x + f.y + f.z + f.w;
    sp += f.x * a.x + f.y * a.y + f.z * a.z + f.w * a.w;
    sq += f.x * b.x + f.y * b.y + f.z * b.z + f.w * b.w;
  }
#pragma unroll
  for (int off = 1; off < 64; off <<= 1) {
    sr += __shfl_xor(sr, off, 64);
    sp += __shfl_xor(sp, off, 64);
    sq += __shfl_xor(sq, off, 64);
  }
  if (lane == 0) {
    rv[row] = sr;
    pv[row] = sp;
    qv[row] = sq;
  }
}

// ---- S-residual + deferred softmax: Pt = exp(s - m_tile) f16, stats ----
// 256x256 tile, 2-buffer, 2-MFMA (R10 loop). LDS: Th Tl xh (48KiB x2).
__global__ __launch_bounds__(512, 1) void k_qkt(
    const f16* __restrict__ Ah, const f16* __restrict__ Al,
    const f16* __restrict__ Bx, const float* __restrict__ rv,
    const float* __restrict__ pv, const float* __restrict__ qv,
    f16* __restrict__ Pt, float* __restrict__ mtile,
    float* __restrict__ tsum) {
  char* smem = dsm;
  constexpr int K = 1024, N = 4096, nT = 32, BUF = 49152;
  const int tid = threadIdx.x;
  const int lane = tid & 63, wv = tid >> 6;
  const int wm = wv >> 2, wn = wv & 3;
  const int bid = blockIdx.x;
  const int wg = (bid & 7) * 32 + (bid >> 3);
  const int bx = wg >> 4, by = wg & 15;
  const int brow = bx * 256, bcol = by * 256;

  const int srow16 = lane >> 2;
  const int sslot = (lane & 3) ^ ((lane >> 3) & 3);

  const f16* bases[3] = {Ah, Al, Bx};
  const int rbase[3] = {brow, brow, bcol};

  auto stage3 = [&](int buf, int t, int half) {
    const int kt = t * 32;
    char* bb = smem + BUF * buf;
#pragma unroll
    for (int j = 0; j < 3; ++j) {
      const int g = wv * 6 + half * 3 + j;
      const int rg = g >> 4, gm = g & 15;
      gload16(
          bases[rg] + (size_t)(rbase[rg] + gm * 16 + srow16) * K + kt + 8 * sslot,
          bb + rg * 16384 + gm * 1024);
    }
  };

  f32x16 acc[4][2] = {};
  const int l31 = lane & 31, ch0 = lane >> 5;
  const int arow0 = wm * 128 + l31;
  const int brow0 = wn * 64 + l31;

  stage3(0, 0, 0);
  stage3(0, 0, 1);

  for (int t = 0; t < nT; ++t) {
    const int cur = t & 1;
    const char* bb = smem + BUF * cur;
    const bool pre = t < nT - 1;
    if (pre) {
      stage3(cur ^ 1, t + 1, 0);
      __builtin_amdgcn_sched_barrier(0);
      asm volatile("s_waitcnt vmcnt(3)" ::: "memory");
    } else {
      asm volatile("s_waitcnt vmcnt(0)" ::: "memory");
    }
    __builtin_amdgcn_sched_barrier(0);
    __builtin_amdgcn_s_barrier();
    __builtin_amdgcn_sched_barrier(0);
#pragma unroll
    for (int ks = 0; ks < 2; ++ks) {
      const int ch = ks * 2 + ch0;
      f16x8 a_h[4], a_l[4], b_h[2];
#pragma unroll
      for (int fm = 0; fm < 4; ++fm) {
        const int r = arow0 + fm * 32;
        const int off = r * 64 + 16 * (ch ^ ((r >> 1) & 3));
        a_h[fm] = *(const f16x8*)(bb + off);
        a_l[fm] = *(const f16x8*)(bb + 16384 + off);
      }
#pragma unroll
      for (int fn = 0; fn < 2; ++fn) {
        const int r = brow0 + fn * 32;
        const int off = r * 64 + 16 * (ch ^ ((r >> 1) & 3));
        b_h[fn] = *(const f16x8*)(bb + 32768 + off);
      }
      if (ks == 0 && pre) stage3(cur ^ 1, t + 1, 1);
      __builtin_amdgcn_sched_barrier(0);
      asm volatile("s_waitcnt lgkmcnt(0)" ::: "memory");
      __builtin_amdgcn_sched_barrier(0);
      __builtin_amdgcn_s_setprio(1);
#pragma unroll
      for (int fm = 0; fm < 4; ++fm)
#pragma unroll
        for (int fn = 0; fn < 2; ++fn) {
          acc[fm][fn] = __builtin_amdgcn_mfma_f32_32x32x16_f16(
              a_h[fm], b_h[fn], acc[fm][fn], 0, 0, 0);
          acc[fm][fn] = __builtin_amdgcn_mfma_f32_32x32x16_f16(
              a_l[fm], b_h[fn], acc[fm][fn], 0, 0, 0);
        }
      __builtin_amdgcn_s_setprio(0);
      __builtin_amdgcn_sched_barrier(0);
      __builtin_amdgcn_s_barrier();
    }
  }

  // ---- epilogue: rank-1 add, per-tile-row max/sum, Pt = exp(s - m) ----
  float* red = (float*)smem;  // [64][4], reused per fm block
  const int col0 = bcol + wn * 64 + l31;        // fn=0 col
  const float rc0 = rv[col0], qc0 = qv[col0];
  const float rc1 = rv[col0 + 32], qc1 = qv[col0 + 32];
#pragma unroll
  for (int fm = 0; fm < 4; ++fm) {
    float mm[16], ss[16];
    int rin[16];
#pragma unroll
    for (int j = 0; j < 16; ++j) {
      rin[j] = (j & 3) + 8 * (j >> 2) + 4 * ch0;
      const int row = brow + wm * 128 + fm * 32 + rin[j];
      const float rr = rv[row], pr = pv[row];
      acc[fm][0][j] += 8.0f * rr * rc0 + (pr * rc0 + rr * qc0) * 0.015625f;
      acc[fm][1][j] += 8.0f * rr * rc1 + (pr * rc1 + rr * qc1) * 0.015625f;
      mm[j] = fmaxf(acc[fm][0][j], acc[fm][1][j]);
    }
    // cross-lane max over the 32-lane col group (stays within ch0 half)
#pragma unroll
    for (int off = 1; off < 32; off <<= 1)
#pragma unroll
      for (int j = 0; j < 16; ++j) mm[j] = fmaxf(mm[j], __shfl_xor(mm[j], off, 64));
    if (l31 == 0)
#pragma unroll
      for (int j = 0; j < 16; ++j) red[(wm * 32 + rin[j]) * 4 + wn] = mm[j];
    __syncthreads();
#pragma unroll
    for (int j = 0; j < 16; ++j) {
      const int b = (wm * 32 + rin[j]) * 4;
      mm[j] = fmaxf(fmaxf(red[b], red[b + 1]), fmaxf(red[b + 2], red[b + 3]));
    }
    __syncthreads();  // all reads done before red reuse
    // exp + store Pt + col-sum
#pragma unroll
    for (int j = 0; j < 16; ++j) {
      const float e0 = __expf(acc[fm][0][j] - mm[j]);
      const float e1 = __expf(acc[fm][1][j] - mm[j]);
      const int row = brow + wm * 128 + fm * 32 + rin[j];
      Pt[(size_t)row * N + col0] = (f16)e0;
      Pt[(size_t)row * N + col0 + 32] = (f16)e1;
      ss[j] = e0 + e1;
    }
#pragma unroll
    for (int off = 1; off < 32; off <<= 1)
#pragma unroll
      for (int j = 0; j < 16; ++j) ss[j] += __shfl_xor(ss[j], off, 64);
    if (l31 == 0)
#pragma unroll
      for (int j = 0; j < 16; ++j) red[(wm * 32 + rin[j]) * 4 + wn] = ss[j];
    __syncthreads();
    if (wn == 0 && l31 == 0) {
#pragma unroll
      for (int j = 0; j < 16; ++j) {
        const int b = (wm * 32 + rin[j]) * 4;
        const float tv = red[b] + red[b + 1] + red[b + 2] + red[b + 3];
        const int row = brow + wm * 128 + fm * 32 + rin[j];
        mtile[row * 16 + by] = mm[j];
        tsum[row * 16 + by] = tv;
      }
    }
    __syncthreads();  // red reuse next fm
  }
}

// ---- scale[row][t] = e^{mtile-m}/sum ----
__global__ __launch_bounds__(256) void k_scale(const float* __restrict__ mtile,
                                               const float* __restrict__ tsum,
                                               float* __restrict__ scale) {
  const int row = blockIdx.x * 256 + threadIdx.x;
  float mt[16];
  float m = -3.4e38f;
#pragma unroll
  for (int t = 0; t < 16; ++t) {
    mt[t] = mtile[row * 16 + t];
    m = fmaxf(m, mt[t]);
  }
  float sum = 0.f;
#pragma unroll
  for (int t = 0; t < 16; ++t) sum += tsum[row * 16 + t] * __expf(mt[t] - m);
  const float inv = 1.0f / sum;
#pragma unroll
  for (int t = 0; t < 16; ++t) scale[row * 16 + t] = __expf(mt[t] - m) * inv;
}

// ---- P = Pt * scale[row][col>>8] ----
__global__ __launch_bounds__(256) void k_rescale(const f16* __restrict__ Pt,
                                                 const float* __restrict__ scale,
                                                 f16* __restrict__ P) {
  const size_t i = (size_t)blockIdx.x * 256 + threadIdx.x;  // f16x8 chunks
  f16x8 v = ((const f16x8*)Pt)[i];
  const float sc = scale[(i >> 9) * 16 + ((i & 511) >> 5)];
  f16x8 o;
#pragma unroll
  for (int k = 0; k < 8; ++k) o[k] = (f16)((float)v[k] * sc);
  ((f16x8*)P)[i] = o;
}

// ---- depth-3 pipelined BT-GEMM: C[M][N] = A[M][K] . B[N][K]^T ----
template <int K, int NBY, int OUT>
__global__ __launch_bounds__(512, 1) void pipe_bt(const f16* __restrict__ A,
                                                  const f16* __restrict__ B,
                                                  float* __restrict__ outf,
                                                  f16* __restrict__ outh,
                                                  int ldo) {
  char* smem = dsm;
  constexpr int nT = K / 32, BUF = 16384;
  const int tid = threadIdx.x;
  const int lane = tid & 63, wv = tid >> 6;
  const int wm = wv >> 2, wn = wv & 3;
  const int bid = blockIdx.x;
  const int wg = (bid & 7) * 32 + (bid >> 3);
  const int bx = wg / NBY, by = wg % NBY;
  const int brow = bx * 128, bcol = by * 128;

  const int srow16 = lane >> 2;
  const int sslot = (lane & 3) ^ ((lane >> 3) & 3);
  const int sreg = wv >> 2;
  const f16* __restrict__ sbase = sreg ? B : A;
  const int rbase = sreg ? bcol : brow;

  auto stage = [&](int buf, int t) {
    const int kt = t * 32;
    char* bb = smem + BUF * buf + sreg * 8192;
#pragma unroll
    for (int j = 0; j < 2; ++j) {
      const int g = (wv & 3) * 2 + j;
      gload16(sbase + (size_t)(rbase + g * 16 + srow16) * K + kt + 8 * sslot,
              bb + g * 1024);
    }
  };

  f32x16 acc[2] = {};
  const int l31 = lane & 31, ch0 = lane >> 5;
  const int arow0 = wm * 64 + l31;
  const int brow0 = wn * 32 + l31;

  stage(0, 0);
  stage(1, 1);
  stage(2, 2);

  for (int t = 0; t < nT; ++t) {
    const int rem = nT - 1 - t;
    if (rem >= 3) stage((t + 3) & 3, t + 3);
    __builtin_amdgcn_sched_barrier(0);
    if (rem >= 3) {
      asm volatile("s_waitcnt vmcnt(6)" ::: "memory");
    } else if (rem == 2) {
      asm volatile("s_waitcnt vmcnt(4)" ::: "memory");
    } else if (rem == 1) {
      asm volatile("s_waitcnt vmcnt(2)" ::: "memory");
    } else {
      asm volatile("s_waitcnt vmcnt(0)" ::: "memory");
    }
    __builtin_amdgcn_sched_barrier(0);
    __builtin_amdgcn_s_barrier();
    __builtin_amdgcn_sched_barrier(0);
    const char* bb = smem + BUF * (t & 3);
#pragma unroll
    for (int ks = 0; ks < 2; ++ks) {
      const int ch = ks * 2 + ch0;
      f16x8 a_h[2], b_h;
#pragma unroll
      for (int fm = 0; fm < 2; ++fm) {
        const int r = arow0 + fm * 32;
        a_h[fm] = *(const f16x8*)(bb + r * 64 + 16 * (ch ^ ((r >> 1) & 3)));
      }
      b_h = *(const f16x8*)(bb + 8192 + brow0 * 64 +
                            16 * (ch ^ ((brow0 >> 1) & 3)));
      __builtin_amdgcn_sched_barrier(0);
      asm volatile("s_waitcnt lgkmcnt(0)" ::: "memory");
      __builtin_amdgcn_sched_barrier(0);
      __builtin_amdgcn_s_setprio(1);
#pragma unroll
      for (int fm = 0; fm < 2; ++fm)
        acc[fm] = __builtin_amdgcn_mfma_f32_32x32x16_f16(a_h[fm], b_h, acc[fm],
                                                         0, 0, 0);
      __builtin_amdgcn_s_setprio(0);
      __builtin_amdgcn_sched_barrier(0);
    }
    __builtin_amdgcn_s_barrier();
  }

#pragma unroll
  for (int fm = 0; fm < 2; ++fm) {
    const int col = bcol + wn * 32 + l31;
#pragma unroll
    for (int j = 0; j < 16; ++j) {
      const int row =
          brow + wm * 64 + fm * 32 + (j & 3) + 8 * (j >> 2) + 4 * ch0;
      if constexpr (OUT == 0) {
        outf[(size_t)row * ldo + col] = acc[fm][j];
      } else {
        outh[(size_t)row * ldo + col] = (f16)acc[fm][j];
      }
    }
  }
}

// ---- generic BT-GEMM (m97-style) ----
template <int NM, int OUT>
__global__ __launch_bounds__(256) void gemm_bt(
    const f16* __restrict__ A, const f16* __restrict__ Al,
    const f16* __restrict__ B, const f16* __restrict__ Bl, int K,
    f16* __restrict__ oh, f16* __restrict__ ol, int ldo, float scale,
    const float* __restrict__ sav, const float* __restrict__ sbv) {
  f16* smem = (f16*)dsm;
  f16* tAh = smem;
  f16* tBh = smem + 8192;
  f16* tAl = smem + 16384;
  f16* tBl = smem + 24576;

  const int tid = threadIdx.x;
  const int lane = tid & 63, wid = tid >> 6;
  const int wr = wid >> 1, wc = wid & 1;
  const int brow = blockIdx.x * 128, bcol = blockIdx.y * 128;
  const int ar = lane & 15, k0 = (lane >> 4) * 8;
  const int crow = lane >> 3, ccol = (lane & 7) * 8;

  f32x4 acc[4][4] = {};
  const size_t aoff = (size_t)crow * K + ccol;

  for (int kt = 0; kt < K; kt += 64) {
    const f16* Ab = A + (size_t)brow * K + kt;
    const f16* Bb = B + (size_t)bcol * K + kt;
#pragma unroll
    for (int cc = 0; cc < 4; ++cc) {
      const int c = wid * 4 + cc;
      const size_t co = (size_t)c * 8 * K + aoff;
      gload16(Ab + co, tAh + c * 512);
      gload16(Bb + co, tBh + c * 512);
      if constexpr (NM >= 2) gload16(Al + (size_t)brow * K + kt + co, tAl + c * 512);
      if constexpr (NM == 3) gload16(Bl + (size_t)bcol * K + kt + co, tBl + c * 512);
    }
    __syncthreads();
#pragma unroll
    for (int ks = 0; ks < 2; ++ks) {
      f16x8 ah[4], bh[4], alv[4], blv[4];
#pragma unroll
      for (int m = 0; m < 4; ++m) {
        ah[m] = *(const f16x8*)&tAh[(wr * 64 + m * 16 + ar) * 64 + ks * 32 + k0];
        bh[m] = *(const f16x8*)&tBh[(wc * 64 + m * 16 + ar) * 64 + ks * 32 + k0];
        if constexpr (NM >= 2)
          alv[m] = *(const f16x8*)&tAl[(wr * 64 + m * 16 + ar) * 64 + ks * 32 + k0];
        if constexpr (NM == 3)
          blv[m] = *(const f16x8*)&tBl[(wc * 64 + m * 16 + ar) * 64 + ks * 32 + k0];
      }
#pragma unroll
      for (int m = 0; m < 4; ++m)
#pragma unroll
        for (int n = 0; n < 4; ++n) {
          acc[m][n] = __builtin_amdgcn_mfma_f32_16x16x32_f16(ah[m], bh[n], acc[m][n], 0, 0, 0);
          if constexpr (NM >= 2)
            acc[m][n] = __builtin_amdgcn_mfma_f32_16x16x32_f16(alv[m], bh[n], acc[m][n], 0, 0, 0);
          if constexpr (NM == 3)
            acc[m][n] = __builtin_amdgcn_mfma_f32_16x16x32_f16(ah[m], blv[n], acc[m][n], 0, 0, 0);
        }
    }
    __syncthreads();
  }

#pragma unroll
  for (int m = 0; m < 4; ++m)
#pragma unroll
    for (int n = 0; n < 4; ++n)
#pragma unroll
      for (int j = 0; j < 4; ++j) {
        const int row = brow + wr * 64 + m * 16 + (lane >> 4) * 4 + j;
        const int col = bcol + wc * 64 + n * 16 + ar;
        const size_t idx = (size_t)row * ldo + col;
        if constexpr (OUT == 1) {
          f16 h, l;
          split_f32(acc[m][n][j] * scale, h, l);
          oh[idx] = h;
          ol[idx] = l;
        } else {  // OUT == 4: rank1-subtract, h only
          const float v =
              (acc[m][n][j] - 256.0f - 0.5f * sav[col] - 0.5f * sbv[row]) * scale;
          oh[idx] = (f16)v;
        }
      }
}

extern "C" void kernel_launch(void* const* d_in, const int* in_sizes, int n_in,
                              void* d_out, int out_size, void* d_ws,
                              size_t ws_size, hipStream_t stream) {
  const float* x = (const float*)d_in[0];
  const float* Wq = (const float*)d_in[1];
  const float* Wk = (const float*)d_in[2];
  const float* Wv = (const float*)d_in[3];
  float* out = (float*)d_out;
  char* ws = (char*)d_ws;
  const size_t MiB = 1u << 20;
  f16* xh = (f16*)(ws + 0 * MiB);
  f16* xl = (f16*)(ws + 8 * MiB);
  f16* Th = (f16*)(ws + 16 * MiB);
  f16* Tl = (f16*)(ws + 24 * MiB);
  f16* Vt = (f16*)(ws + 32 * MiB);
  f16* Pt = (f16*)(ws + 40 * MiB);          // 32 MiB
  float* mtile = (float*)(ws + 72 * MiB);   // 256 KiB
  float* tsum = (float*)(ws + 73 * MiB);    // 256 KiB
  float* scalebuf = (float*)(ws + 74 * MiB);
  f16* Pm = (f16*)(ws + 0 * MiB);           // after k_rescale
  f16* Wqh = (f16*)(ws + 40 * MiB);         // dead-Pt-region temps (pre-k_qkt)
  f16* Wql = (f16*)(ws + 42 * MiB);
  f16* Wkh = (f16*)(ws + 44 * MiB);
  f16* Wkl = (f16*)(ws + 46 * MiB);
  f16* Mth = (f16*)(ws + 48 * MiB);
  f16* Wtvh = (f16*)(ws + 52 * MiB);
  float* sa = (float*)(ws + 54 * MiB);
  float* sb = (float*)(ws + 54 * MiB + 65536);
  float* rv = (float*)(ws + 8 * MiB);
  float* pv = (float*)(ws + 8 * MiB + 65536);
  float* qv = (float*)(ws + 8 * MiB + 131072);

  (void)hipFuncSetAttribute((const void*)k_qkt,
                            hipFuncAttributeMaxDynamicSharedMemorySize, 98304);
  (void)hipFuncSetAttribute((const void*)pipe_bt<4096, 8, 0>,
                            hipFuncAttributeMaxDynamicSharedMemorySize, 65536);
  (void)hipFuncSetAttribute((const void*)pipe_bt<1024, 32, 2>,
                            hipFuncAttributeMaxDynamicSharedMemorySize, 65536);

  k_split<<<dim3(1024, 1, 3), 256, 0, stream>>>(x, Wq, Wk, xh, xl, Wqh, Wql,
                                                Wkh, Wkl);
  k_wsplit_v<<<dim3(16, 16), 256, 0, stream>>>(Wv, Wtvh);
  k_rowsums<<<dim3(256, 2), 256, 0, stream>>>(Wq, Wk, sa, sb);
  gemm_bt<3, 4><<<dim3(8, 8), 256, 65536, stream>>>(
      Wkh, Wkl, Wqh, Wql, 1024, Mth, nullptr, 1024, 0.03125f, sa, sb);
  gemm_bt<2, 1><<<dim3(32, 8), 256, 49152, stream>>>(
      xh, xl, Mth, nullptr, 1024, Th, Tl, 1024, 1.0f, nullptr, nullptr);
  pipe_bt<1024, 32, 2><<<dim3(256), 512, 65536, stream>>>(Wtvh, xh, nullptr,
                                                          Vt, 4096);
  k_rpq<<<dim3(1024), 256, 0, stream>>>(x, sa, sb, rv, pv, qv);
  k_qkt<<<dim3(256), 512, 98304, stream>>>(Th, Tl, xh, rv, pv, qv, Pt, mtile,
                                           tsum);
  k_scale<<<dim3(16), 256, 0, stream>>>(mtile, tsum, scalebuf);
  k_rescale<<<dim3(8192), 256, 0, stream>>>(Pt, scalebuf, Pm);
  pipe_bt<4096, 8, 0><<<dim3(256), 512, 65536, stream>>>(Pm, Vt, out, nullptr,
                                                         1024);
}

// Round 14
// 253.456 us; speedup vs baseline: 1.0402x; 1.0402x over previous
//
#include <hip/hip_runtime.h>

// SelfAttention: out = softmax((xWq)(xWk)^T/32) @ (xWv), f32, S=4096, D=1024.
// R14: deferred per-tile softmax, done right. k_qkt epilogue dumps the
// rank-1-corrected S-tile to LDS and row-reduces coalesced (cheap), writing
// Pt = exp(s - m_tile) f16 + {mtile,tsum}. k_scale builds transposed
// scale_t[16][4096]. PV folds scale per-8-K-step chunk from an 8KB LDS copy
// (lgkm domain - vmcnt pipeline untouched). No softmax / rescale kernels.
// scores = 8rr^T + (pr^T+rq^T)/64 + (x·(Mres/32))·x^T.
// ws (MiB): xh 0, xl 8 (r/p/q overlay), Th 16, Tl 24, Vt 32, Pt 40..72,
//   mtile 72, tsum 73, scale_t 74; temps in dead-Pt: Wqh 40.., Mth 48,
//   Wtvh 52, sa/sb 54.

typedef _Float16 f16;
typedef f16 f16x8 __attribute__((ext_vector_type(8)));
typedef f16 f16x4v __attribute__((ext_vector_type(4)));
typedef float f32x4 __attribute__((ext_vector_type(4)));
typedef float f32x16 __attribute__((ext_vector_type(16)));
typedef unsigned short u16;
typedef u16 u16x8 __attribute__((ext_vector_type(8)));

extern __shared__ char dsm[];  // single dynamic-LDS symbol for the whole TU

__device__ __forceinline__ void split_f32(float v, f16& h, f16& l) {
  h = (f16)v;
  l = (f16)(v - (float)h);
}

__device__ __forceinline__ void gload16(const void* g, void* l) {
  __builtin_amdgcn_global_load_lds(
      (const __attribute__((address_space(1))) void*)g,
      (__attribute__((address_space(3))) void*)l, 16, 0, 0);
}

// ---- prep: elementwise split f32 -> (h,l) f16 for x, Wq, Wk ----
__global__ __launch_bounds__(256) void k_split(
    const float* __restrict__ x, const float* __restrict__ wq,
    const float* __restrict__ wk, f16* __restrict__ xh, f16* __restrict__ xl,
    f16* __restrict__ qh, f16* __restrict__ ql, f16* __restrict__ kh,
    f16* __restrict__ kl) {
  const int z = blockIdx.z;
  const float* __restrict__ src = (z == 0) ? x : (z == 1) ? wq : wk;
  f16* __restrict__ oh = (z == 0) ? xh : (z == 1) ? qh : kh;
  f16* __restrict__ ol = (z == 0) ? xl : (z == 1) ? ql : kl;
  const int n4 = (z == 0) ? (4096 * 1024 / 4) : (1024 * 1024 / 4);
  for (int i = blockIdx.x * 256 + threadIdx.x; i < n4; i += 1024 * 256) {
    float4 f = ((const float4*)src)[i];
    f16x4v h, l;
    f16 hh, ll;
    split_f32(f.x, hh, ll); h[0] = hh; l[0] = ll;
    split_f32(f.y, hh, ll); h[1] = hh; l[1] = ll;
    split_f32(f.z, hh, ll); h[2] = hh; l[2] = ll;
    split_f32(f.w, hh, ll); h[3] = hh; l[3] = ll;
    ((f16x4v*)oh)[i] = h;
    ((f16x4v*)ol)[i] = l;
  }
}

// ---- prep: transpose+split-h Wv [a][d] f32 -> Wtvh [d][a] f16 ----
__global__ __launch_bounds__(256) void k_wsplit_v(const float* __restrict__ Wv,
                                                  f16* __restrict__ vt) {
  __shared__ float sh[64][65];
  const int kb = blockIdx.x * 64, nb = blockIdx.y * 64;
  const int t = threadIdx.x;
  const int r = t >> 2, c4 = (t & 3) * 16;
#pragma unroll
  for (int i = 0; i < 4; ++i) {
    float4 f = *(const float4*)&Wv[(size_t)(kb + r) * 1024 + nb + c4 + i * 4];
    sh[r][c4 + i * 4 + 0] = f.x;
    sh[r][c4 + i * 4 + 1] = f.y;
    sh[r][c4 + i * 4 + 2] = f.z;
    sh[r][c4 + i * 4 + 3] = f.w;
  }
  __syncthreads();
  const int n = t >> 2, ks = (t & 3) * 16;
  u16x8 h0, h1;
#pragma unroll
  for (int i = 0; i < 8; ++i) {
    h0[i] = __builtin_bit_cast(u16, (f16)sh[ks + i][n]);
    h1[i] = __builtin_bit_cast(u16, (f16)sh[ks + 8 + i][n]);
  }
  const size_t o = (size_t)(nb + n) * 1024 + kb + ks;
  *(u16x8*)&vt[o] = h0;
  *(u16x8*)&vt[o + 8] = h1;
}

// ---- prep: centered row sums ----
__global__ __launch_bounds__(256) void k_rowsums(const float* __restrict__ Wq,
                                                 const float* __restrict__ Wk,
                                                 float* __restrict__ sa,
                                                 float* __restrict__ sb) {
  const int z = blockIdx.y;
  const float* __restrict__ W = z ? Wk : Wq;
  float* __restrict__ o = z ? sb : sa;
  const int row = blockIdx.x * 4 + (threadIdx.x >> 6);
  const int lane = threadIdx.x & 63;
  const float4* src = (const float4*)(W + (size_t)row * 1024);
  float s = 0.f;
#pragma unroll
  for (int i = 0; i < 4; ++i) {
    float4 f = src[lane + 64 * i];
    s += f.x + f.y + f.z + f.w;
  }
#pragma unroll
  for (int off = 1; off < 64; off <<= 1) s += __shfl_xor(s, off, 64);
  if (lane == 0) o[row] = s - 512.0f;
}

// ---- prep: r = x*1, p = x*sa, q = x*sb ----
__global__ __launch_bounds__(256) void k_rpq(
    const float* __restrict__ x, const float* __restrict__ sa,
    const float* __restrict__ sb, float* __restrict__ rv,
    float* __restrict__ pv, float* __restrict__ qv) {
  const int row = blockIdx.x * 4 + (threadIdx.x >> 6);
  const int lane = threadIdx.x & 63;
  const float* xr = x + (size_t)row * 1024;
  float sr = 0.f, sp = 0.f, sq = 0.f;
#pragma unroll
  for (int i = 0; i < 4; ++i) {
    const int c = (lane + 64 * i) * 4;
    float4 f = *(const float4*)&xr[c];
    float4 a = *(const float4*)&sa[c];
    float4 b = *(const float4*)&sb[c];
    sr += f.x + f.y + f.z + f.w;
    sp += f.x * a.x + f.y * a.y + f.z * a.z + f.w * a.w;
    sq += f.x * b.x + f.y * b.y + f.z * b.z + f.w * b.w;
  }
#pragma unroll
  for (int off = 1; off < 64; off <<= 1) {
    sr += __shfl_xor(sr, off, 64);
    sp += __shfl_xor(sp, off, 64);
    sq += __shfl_xor(sq, off, 64);
  }
  if (lane == 0) {
    rv[row] = sr;
    pv[row] = sp;
    qv[row] = sq;
  }
}

// ---- S-residual + deferred softmax (LDS epilogue) ----
// 256x256 tile, 2-buffer, 2-MFMA (R10 loop). LDS: Th Tl xh (48KiB x2);
// epilogue reuses smem as sS[64][260] f32 (66.5KB).
__global__ __launch_bounds__(512, 1) void k_qkt(
    const f16* __restrict__ Ah, const f16* __restrict__ Al,
    const f16* __restrict__ Bx, const float* __restrict__ rv,
    const float* __restrict__ pv, const float* __restrict__ qv,
    f16* __restrict__ Pt, float* __restrict__ mtile,
    float* __restrict__ tsum) {
  char* smem = dsm;
  constexpr int K = 1024, N = 4096, nT = 32, BUF = 49152;
  const int tid = threadIdx.x;
  const int lane = tid & 63, wv = tid >> 6;
  const int wm = wv >> 2, wn = wv & 3;
  const int bid = blockIdx.x;
  const int wg = (bid & 7) * 32 + (bid >> 3);
  const int bx = wg >> 4, by = wg & 15;
  const int brow = bx * 256, bcol = by * 256;

  const int srow16 = lane >> 2;
  const int sslot = (lane & 3) ^ ((lane >> 3) & 3);

  const f16* bases[3] = {Ah, Al, Bx};
  const int rbase[3] = {brow, brow, bcol};

  auto stage3 = [&](int buf, int t, int half) {
    const int kt = t * 32;
    char* bb = smem + BUF * buf;
#pragma unroll
    for (int j = 0; j < 3; ++j) {
      const int g = wv * 6 + half * 3 + j;
      const int rg = g >> 4, gm = g & 15;
      gload16(
          bases[rg] + (size_t)(rbase[rg] + gm * 16 + srow16) * K + kt + 8 * sslot,
          bb + rg * 16384 + gm * 1024);
    }
  };

  f32x16 acc[4][2] = {};
  const int l31 = lane & 31, ch0 = lane >> 5;
  const int arow0 = wm * 128 + l31;
  const int brow0 = wn * 64 + l31;

  stage3(0, 0, 0);
  stage3(0, 0, 1);

  for (int t = 0; t < nT; ++t) {
    const int cur = t & 1;
    const char* bb = smem + BUF * cur;
    const bool pre = t < nT - 1;
    if (pre) {
      stage3(cur ^ 1, t + 1, 0);
      __builtin_amdgcn_sched_barrier(0);
      asm volatile("s_waitcnt vmcnt(3)" ::: "memory");
    } else {
      asm volatile("s_waitcnt vmcnt(0)" ::: "memory");
    }
    __builtin_amdgcn_sched_barrier(0);
    __builtin_amdgcn_s_barrier();
    __builtin_amdgcn_sched_barrier(0);
#pragma unroll
    for (int ks = 0; ks < 2; ++ks) {
      const int ch = ks * 2 + ch0;
      f16x8 a_h[4], a_l[4], b_h[2];
#pragma unroll
      for (int fm = 0; fm < 4; ++fm) {
        const int r = arow0 + fm * 32;
        const int off = r * 64 + 16 * (ch ^ ((r >> 1) & 3));
        a_h[fm] = *(const f16x8*)(bb + off);
        a_l[fm] = *(const f16x8*)(bb + 16384 + off);
      }
#pragma unroll
      for (int fn = 0; fn < 2; ++fn) {
        const int r = brow0 + fn * 32;
        const int off = r * 64 + 16 * (ch ^ ((r >> 1) & 3));
        b_h[fn] = *(const f16x8*)(bb + 32768 + off);
      }
      if (ks == 0 && pre) stage3(cur ^ 1, t + 1, 1);
      __builtin_amdgcn_sched_barrier(0);
      asm volatile("s_waitcnt lgkmcnt(0)" ::: "memory");
      __builtin_amdgcn_sched_barrier(0);
      __builtin_amdgcn_s_setprio(1);
#pragma unroll
      for (int fm = 0; fm < 4; ++fm)
#pragma unroll
        for (int fn = 0; fn < 2; ++fn) {
          acc[fm][fn] = __builtin_amdgcn_mfma_f32_32x32x16_f16(
              a_h[fm], b_h[fn], acc[fm][fn], 0, 0, 0);
          acc[fm][fn] = __builtin_amdgcn_mfma_f32_32x32x16_f16(
              a_l[fm], b_h[fn], acc[fm][fn], 0, 0, 0);
        }
      __builtin_amdgcn_s_setprio(0);
      __builtin_amdgcn_sched_barrier(0);
      __builtin_amdgcn_s_barrier();
    }
  }

  // ---- epilogue: rank-1 add -> LDS tile -> coalesced row softmax ----
  float* sS = (float*)smem;  // [64][260] f32
  const int colg = bcol + wn * 64 + l31;
  const float rc0 = rv[colg], qc0 = qv[colg];
  const float rc1 = rv[colg + 32], qc1 = qv[colg + 32];
#pragma unroll
  for (int fm = 0; fm < 4; ++fm) {
#pragma unroll
    for (int j = 0; j < 16; ++j) {
      const int rl = (j & 3) + 8 * (j >> 2) + 4 * ch0;  // 0..31
      const int row = brow + wm * 128 + fm * 32 + rl;
      const float rr = rv[row], pr = pv[row];
      const int rl2 = wm * 32 + rl;
      sS[rl2 * 260 + wn * 64 + l31] =
          acc[fm][0][j] + 8.0f * rr * rc0 + (pr * rc0 + rr * qc0) * 0.015625f;
      sS[rl2 * 260 + wn * 64 + l31 + 32] =
          acc[fm][1][j] + 8.0f * rr * rc1 + (pr * rc1 + rr * qc1) * 0.015625f;
    }
    __syncthreads();
#pragma unroll
    for (int rr8 = 0; rr8 < 8; ++rr8) {
      const int rl2 = wv * 8 + rr8;
      float4 v4 = *(const float4*)&sS[rl2 * 260 + lane * 4];
      float m = fmaxf(fmaxf(v4.x, v4.y), fmaxf(v4.z, v4.w));
#pragma unroll
      for (int off = 1; off < 64; off <<= 1)
        m = fmaxf(m, __shfl_xor(m, off, 64));
      const float e0 = __expf(v4.x - m), e1 = __expf(v4.y - m);
      const float e2 = __expf(v4.z - m), e3 = __expf(v4.w - m);
      float sm = e0 + e1 + e2 + e3;
#pragma unroll
      for (int off = 1; off < 64; off <<= 1) sm += __shfl_xor(sm, off, 64);
      const int row = brow + (rl2 >> 5) * 128 + fm * 32 + (rl2 & 31);
      f16x4v pv4;
      pv4[0] = (f16)e0; pv4[1] = (f16)e1; pv4[2] = (f16)e2; pv4[3] = (f16)e3;
      *(f16x4v*)&Pt[(size_t)row * N + bcol + lane * 4] = pv4;
      if (lane == 0) {
        mtile[row * 16 + by] = m;
        tsum[row * 16 + by] = sm;
      }
    }
    __syncthreads();
  }
}

// ---- scale_t[t][row] = e^{mtile-m}/sum (transposed for PV staging) ----
__global__ __launch_bounds__(256) void k_scale(const float* __restrict__ mtile,
                                               const float* __restrict__ tsum,
                                               float* __restrict__ scale_t) {
  const int row = blockIdx.x * 256 + threadIdx.x;
  float mt[16];
  float m = -3.4e38f;
#pragma unroll
  for (int t = 0; t < 16; ++t) {
    mt[t] = mtile[row * 16 + t];
    m = fmaxf(m, mt[t]);
  }
  float sum = 0.f;
#pragma unroll
  for (int t = 0; t < 16; ++t) sum += tsum[row * 16 + t] * __expf(mt[t] - m);
  const float inv = 1.0f / sum;
#pragma unroll
  for (int t = 0; t < 16; ++t)
    scale_t[t * 4096 + row] = __expf(mt[t] - m) * inv;
}

// ---- PV with folded scale: out = sum_t scale[r,t] * (Pt_chunk · V^T) ----
// depth-3 pipeline, 128x128 tile, 4 LDS bufs x 16KB + 8KB scale slice.
__global__ __launch_bounds__(512, 1) void k_pvs(const f16* __restrict__ P,
                                                const f16* __restrict__ Vt,
                                                const float* __restrict__ scale_t,
                                                float* __restrict__ out) {
  char* smem = dsm;
  constexpr int K = 4096, nT = K / 32, BUF = 16384;
  const int tid = threadIdx.x;
  const int lane = tid & 63, wv = tid >> 6;
  const int wm = wv >> 2, wn = wv & 3;
  const int bid = blockIdx.x;
  const int wg = (bid & 7) * 32 + (bid >> 3);
  const int bx = wg >> 3, by = wg & 7;
  const int brow = bx * 128, bcol = by * 128;

  const int srow16 = lane >> 2;
  const int sslot = (lane & 3) ^ ((lane >> 3) & 3);
  const int sreg = wv >> 2;
  const f16* __restrict__ sbase = sreg ? Vt : P;
  const int rbase = sreg ? bcol : brow;

  // stage scale slice [16][128] into LDS (drained before pipeline starts)
  float* sc_lds = (float*)(smem + 4 * BUF);
  {
    float tmp[4];
#pragma unroll
    for (int i = 0; i < 4; ++i) {
      const int n = tid + i * 512;
      tmp[i] = scale_t[(size_t)(n >> 7) * 4096 + brow + (n & 127)];
    }
#pragma unroll
    for (int i = 0; i < 4; ++i) sc_lds[tid + i * 512] = tmp[i];
    asm volatile("s_waitcnt lgkmcnt(0)" ::: "memory");
  }

  auto stage = [&](int buf, int t) {
    const int kt = t * 32;
    char* bb = smem + BUF * buf + sreg * 8192;
#pragma unroll
    for (int j = 0; j < 2; ++j) {
      const int g = (wv & 3) * 2 + j;
      gload16(sbase + (size_t)(rbase + g * 16 + srow16) * K + kt + 8 * sslot,
              bb + g * 1024);
    }
  };

  f32x16 accp[2] = {};
  f32x16 accf[2] = {};
  const int l31 = lane & 31, ch0 = lane >> 5;
  const int arow0 = wm * 64 + l31;
  const int brow0 = wn * 32 + l31;

  stage(0, 0);
  stage(1, 1);
  stage(2, 2);

  for (int t = 0; t < nT; ++t) {
    const int rem = nT - 1 - t;
    if (rem >= 3) stage((t + 3) & 3, t + 3);
    __builtin_amdgcn_sched_barrier(0);
    if (rem >= 3) {
      asm volatile("s_waitcnt vmcnt(6)" ::: "memory");
    } else if (rem == 2) {
      asm volatile("s_waitcnt vmcnt(4)" ::: "memory");
    } else if (rem == 1) {
      asm volatile("s_waitcnt vmcnt(2)" ::: "memory");
    } else {
      asm volatile("s_waitcnt vmcnt(0)" ::: "memory");
    }
    __builtin_amdgcn_sched_barrier(0);
    __builtin_amdgcn_s_barrier();
    __builtin_amdgcn_sched_barrier(0);
    const char* bb = smem + BUF * (t & 3);
#pragma unroll
    for (int ks = 0; ks < 2; ++ks) {
      const int ch = ks * 2 + ch0;
      f16x8 a_h[2], b_h;
#pragma unroll
      for (int fm = 0; fm < 2; ++fm) {
        const int r = arow0 + fm * 32;
        a_h[fm] = *(const f16x8*)(bb + r * 64 + 16 * (ch ^ ((r >> 1) & 3)));
      }
      b_h = *(const f16x8*)(bb + 8192 + brow0 * 64 +
                            16 * (ch ^ ((brow0 >> 1) & 3)));
      __builtin_amdgcn_sched_barrier(0);
      asm volatile("s_waitcnt lgkmcnt(0)" ::: "memory");
      __builtin_amdgcn_sched_barrier(0);
      __builtin_amdgcn_s_setprio(1);
#pragma unroll
      for (int fm = 0; fm < 2; ++fm)
        accp[fm] = __builtin_amdgcn_mfma_f32_32x32x16_f16(a_h[fm], b_h,
                                                          accp[fm], 0, 0, 0);
      __builtin_amdgcn_s_setprio(0);
      __builtin_amdgcn_sched_barrier(0);
    }
    if ((t & 7) == 7) {  // fold chunk (8 K-steps = one 256-col P tile)
      const int tc = t >> 3;
#pragma unroll
      for (int fm = 0; fm < 2; ++fm)
#pragma unroll
        for (int j = 0; j < 16; ++j) {
          const int rloc =
              wm * 64 + fm * 32 + (j & 3) + 8 * (j >> 2) + 4 * ch0;
          accf[fm][j] += sc_lds[tc * 128 + rloc] * accp[fm][j];
          accp[fm][j] = 0.0f;
        }
    }
    __builtin_amdgcn_s_barrier();
  }

#pragma unroll
  for (int fm = 0; fm < 2; ++fm) {
    const int col = bcol + wn * 32 + l31;
#pragma unroll
    for (int j = 0; j < 16; ++j) {
      const int row =
          brow + wm * 64 + fm * 32 + (j & 3) + 8 * (j >> 2) + 4 * ch0;
      out[(size_t)row * 1024 + col] = accf[fm][j];
    }
  }
}

// ---- depth-3 pipelined BT-GEMM (Vt): C = A . B^T, f16 out ----
template <int K, int NBY>
__global__ __launch_bounds__(512, 1) void pipe_bt(const f16* __restrict__ A,
                                                  const f16* __restrict__ B,
                                                  f16* __restrict__ outh,
                                                  int ldo) {
  char* smem = dsm;
  constexpr int nT = K / 32, BUF = 16384;
  const int tid = threadIdx.x;
  const int lane = tid & 63, wv = tid >> 6;
  const int wm = wv >> 2, wn = wv & 3;
  const int bid = blockIdx.x;
  const int wg = (bid & 7) * 32 + (bid >> 3);
  const int bx = wg / NBY, by = wg % NBY;
  const int brow = bx * 128, bcol = by * 128;

  const int srow16 = lane >> 2;
  const int sslot = (lane & 3) ^ ((lane >> 3) & 3);
  const int sreg = wv >> 2;
  const f16* __restrict__ sbase = sreg ? B : A;
  const int rbase = sreg ? bcol : brow;

  auto stage = [&](int buf, int t) {
    const int kt = t * 32;
    char* bb = smem + BUF * buf + sreg * 8192;
#pragma unroll
    for (int j = 0; j < 2; ++j) {
      const int g = (wv & 3) * 2 + j;
      gload16(sbase + (size_t)(rbase + g * 16 + srow16) * K + kt + 8 * sslot,
              bb + g * 1024);
    }
  };

  f32x16 acc[2] = {};
  const int l31 = lane & 31, ch0 = lane >> 5;
  const int arow0 = wm * 64 + l31;
  const int brow0 = wn * 32 + l31;

  stage(0, 0);
  stage(1, 1);
  stage(2, 2);

  for (int t = 0; t < nT; ++t) {
    const int rem = nT - 1 - t;
    if (rem >= 3) stage((t + 3) & 3, t + 3);
    __builtin_amdgcn_sched_barrier(0);
    if (rem >= 3) {
      asm volatile("s_waitcnt vmcnt(6)" ::: "memory");
    } else if (rem == 2) {
      asm volatile("s_waitcnt vmcnt(4)" ::: "memory");
    } else if (rem == 1) {
      asm volatile("s_waitcnt vmcnt(2)" ::: "memory");
    } else {
      asm volatile("s_waitcnt vmcnt(0)" ::: "memory");
    }
    __builtin_amdgcn_sched_barrier(0);
    __builtin_amdgcn_s_barrier();
    __builtin_amdgcn_sched_barrier(0);
    const char* bb = smem + BUF * (t & 3);
#pragma unroll
    for (int ks = 0; ks < 2; ++ks) {
      const int ch = ks * 2 + ch0;
      f16x8 a_h[2], b_h;
#pragma unroll
      for (int fm = 0; fm < 2; ++fm) {
        const int r = arow0 + fm * 32;
        a_h[fm] = *(const f16x8*)(bb + r * 64 + 16 * (ch ^ ((r >> 1) & 3)));
      }
      b_h = *(const f16x8*)(bb + 8192 + brow0 * 64 +
                            16 * (ch ^ ((brow0 >> 1) & 3)));
      __builtin_amdgcn_sched_barrier(0);
      asm volatile("s_waitcnt lgkmcnt(0)" ::: "memory");
      __builtin_amdgcn_sched_barrier(0);
      __builtin_amdgcn_s_setprio(1);
#pragma unroll
      for (int fm = 0; fm < 2; ++fm)
        acc[fm] = __builtin_amdgcn_mfma_f32_32x32x16_f16(a_h[fm], b_h, acc[fm],
                                                         0, 0, 0);
      __builtin_amdgcn_s_setprio(0);
      __builtin_amdgcn_sched_barrier(0);
    }
    __builtin_amdgcn_s_barrier();
  }

#pragma unroll
  for (int fm = 0; fm < 2; ++fm) {
    const int col = bcol + wn * 32 + l31;
#pragma unroll
    for (int j = 0; j < 16; ++j) {
      const int row =
          brow + wm * 64 + fm * 32 + (j & 3) + 8 * (j >> 2) + 4 * ch0;
      outh[(size_t)row * ldo + col] = (f16)acc[fm][j];
    }
  }
}

// ---- generic BT-GEMM (m97-style) ----
// NM: 3 = AhBh+AhBl+AlBh; 2 = AhBh+AlBh (no Bl).
// OUT: 1 split f16; 4 rank1-subtract then f16 h-only.
template <int NM, int OUT>
__global__ __launch_bounds__(256) void gemm_bt(
    const f16* __restrict__ A, const f16* __restrict__ Al,
    const f16* __restrict__ B, const f16* __restrict__ Bl, int K,
    f16* __restrict__ oh, f16* __restrict__ ol, int ldo, float scale,
    const float* __restrict__ sav, const float* __restrict__ sbv) {
  f16* smem = (f16*)dsm;
  f16* tAh = smem;
  f16* tBh = smem + 8192;
  f16* tAl = smem + 16384;
  f16* tBl = smem + 24576;

  const int tid = threadIdx.x;
  const int lane = tid & 63, wid = tid >> 6;
  const int wr = wid >> 1, wc = wid & 1;
  const int brow = blockIdx.x * 128, bcol = blockIdx.y * 128;
  const int ar = lane & 15, k0 = (lane >> 4) * 8;
  const int crow = lane >> 3, ccol = (lane & 7) * 8;

  f32x4 acc[4][4] = {};
  const size_t aoff = (size_t)crow * K + ccol;

  for (int kt = 0; kt < K; kt += 64) {
    const f16* Ab = A + (size_t)brow * K + kt;
    const f16* Bb = B + (size_t)bcol * K + kt;
#pragma unroll
    for (int cc = 0; cc < 4; ++cc) {
      const int c = wid * 4 + cc;
      const size_t co = (size_t)c * 8 * K + aoff;
      gload16(Ab + co, tAh + c * 512);
      gload16(Bb + co, tBh + c * 512);
      if constexpr (NM >= 2) gload16(Al + (size_t)brow * K + kt + co, tAl + c * 512);
      if constexpr (NM == 3) gload16(Bl + (size_t)bcol * K + kt + co, tBl + c * 512);
    }
    __syncthreads();
#pragma unroll
    for (int ks = 0; ks < 2; ++ks) {
      f16x8 ah[4], bh[4], alv[4], blv[4];
#pragma unroll
      for (int m = 0; m < 4; ++m) {
        ah[m] = *(const f16x8*)&tAh[(wr * 64 + m * 16 + ar) * 64 + ks * 32 + k0];
        bh[m] = *(const f16x8*)&tBh[(wc * 64 + m * 16 + ar) * 64 + ks * 32 + k0];
        if constexpr (NM >= 2)
          alv[m] = *(const f16x8*)&tAl[(wr * 64 + m * 16 + ar) * 64 + ks * 32 + k0];
        if constexpr (NM == 3)
          blv[m] = *(const f16x8*)&tBl[(wc * 64 + m * 16 + ar) * 64 + ks * 32 + k0];
      }
#pragma unroll
      for (int m = 0; m < 4; ++m)
#pragma unroll
        for (int n = 0; n < 4; ++n) {
          acc[m][n] = __builtin_amdgcn_mfma_f32_16x16x32_f16(ah[m], bh[n], acc[m][n], 0, 0, 0);
          if constexpr (NM >= 2)
            acc[m][n] = __builtin_amdgcn_mfma_f32_16x16x32_f16(alv[m], bh[n], acc[m][n], 0, 0, 0);
          if constexpr (NM == 3)
            acc[m][n] = __builtin_amdgcn_mfma_f32_16x16x32_f16(ah[m], blv[n], acc[m][n], 0, 0, 0);
        }
    }
    __syncthreads();
  }

#pragma unroll
  for (int m = 0; m < 4; ++m)
#pragma unroll
    for (int n = 0; n < 4; ++n)
#pragma unroll
      for (int j = 0; j < 4; ++j) {
        const int row = brow + wr * 64 + m * 16 + (lane >> 4) * 4 + j;
        const int col = bcol + wc * 64 + n * 16 + ar;
        const size_t idx = (size_t)row * ldo + col;
        if constexpr (OUT == 1) {
          f16 h, l;
          split_f32(acc[m][n][j] * scale, h, l);
          oh[idx] = h;
          ol[idx] = l;
        } else {  // OUT == 4: rank1-subtract, h only
          const float v =
              (acc[m][n][j] - 256.0f - 0.5f * sav[col] - 0.5f * sbv[row]) * scale;
          oh[idx] = (f16)v;
        }
      }
}

extern "C" void kernel_launch(void* const* d_in, const int* in_sizes, int n_in,
                              void* d_out, int out_size, void* d_ws,
                              size_t ws_size, hipStream_t stream) {
  const float* x = (const float*)d_in[0];
  const float* Wq = (const float*)d_in[1];
  const float* Wk = (const float*)d_in[2];
  const float* Wv = (const float*)d_in[3];
  float* out = (float*)d_out;
  char* ws = (char*)d_ws;
  const size_t MiB = 1u << 20;
  f16* xh = (f16*)(ws + 0 * MiB);
  f16* xl = (f16*)(ws + 8 * MiB);
  f16* Th = (f16*)(ws + 16 * MiB);
  f16* Tl = (f16*)(ws + 24 * MiB);
  f16* Vt = (f16*)(ws + 32 * MiB);
  f16* Pt = (f16*)(ws + 40 * MiB);         // 32 MiB
  float* mtile = (float*)(ws + 72 * MiB);  // 256 KiB
  float* tsum = (float*)(ws + 73 * MiB);   // 256 KiB
  float* scale_t = (float*)(ws + 74 * MiB);
  f16* Wqh = (f16*)(ws + 40 * MiB);        // dead-Pt temps (pre-k_qkt)
  f16* Wql = (f16*)(ws + 42 * MiB);
  f16* Wkh = (f16*)(ws + 44 * MiB);
  f16* Wkl = (f16*)(ws + 46 * MiB);
  f16* Mth = (f16*)(ws + 48 * MiB);
  f16* Wtvh = (f16*)(ws + 52 * MiB);
  float* sa = (float*)(ws + 54 * MiB);
  float* sb = (float*)(ws + 54 * MiB + 65536);
  float* rv = (float*)(ws + 8 * MiB);
  float* pv = (float*)(ws + 8 * MiB + 65536);
  float* qv = (float*)(ws + 8 * MiB + 131072);

  (void)hipFuncSetAttribute((const void*)k_qkt,
                            hipFuncAttributeMaxDynamicSharedMemorySize, 98304);
  (void)hipFuncSetAttribute((const void*)k_pvs,
                            hipFuncAttributeMaxDynamicSharedMemorySize, 73728);
  (void)hipFuncSetAttribute((const void*)pipe_bt<1024, 32>,
                            hipFuncAttributeMaxDynamicSharedMemorySize, 65536);

  k_split<<<dim3(1024, 1, 3), 256, 0, stream>>>(x, Wq, Wk, xh, xl, Wqh, Wql,
                                                Wkh, Wkl);
  k_wsplit_v<<<dim3(16, 16), 256, 0, stream>>>(Wv, Wtvh);
  k_rowsums<<<dim3(256, 2), 256, 0, stream>>>(Wq, Wk, sa, sb);
  gemm_bt<3, 4><<<dim3(8, 8), 256, 65536, stream>>>(
      Wkh, Wkl, Wqh, Wql, 1024, Mth, nullptr, 1024, 0.03125f, sa, sb);
  gemm_bt<2, 1><<<dim3(32, 8), 256, 49152, stream>>>(
      xh, xl, Mth, nullptr, 1024, Th, Tl, 1024, 1.0f, nullptr, nullptr);
  pipe_bt<1024, 32><<<dim3(256), 512, 65536, stream>>>(Wtvh, xh, Vt, 4096);
  k_rpq<<<dim3(1024), 256, 0, stream>>>(x, sa, sb, rv, pv, qv);
  k_qkt<<<dim3(256), 512, 98304, stream>>>(Th, Tl, xh, rv, pv, qv, Pt, mtile,
                                           tsum);
  k_scale<<<dim3(16), 256, 0, stream>>>(mtile, tsum, scale_t);
  k_pvs<<<dim3(256), 512, 73728, stream>>>(Pt, Vt, scale_t, out);
}

// Round 15
// 246.570 us; speedup vs baseline: 1.0692x; 1.0279x over previous
//
#include <hip/hip_runtime.h>

// SelfAttention: out = softmax((xWq)(xWk)^T/32) @ (xWv), f32, S=4096, D=1024.
// R15: R14 with k_qkt waves retiled to 32x256 (acc[8] over fn) so the
// deferred-softmax epilogue is wave-local: in-register fmax over fn + 5
// shfl within the 32-lane half -- no LDS dump, no extra barriers.
// Pt = exp(s - m_tile) f16 + {mtile,tsum}; k_scale -> scale_t[16][4096];
// k_pvs folds scale per-8-K-step chunk from LDS (lgkm domain).
// scores = 8rr^T + (pr^T+rq^T)/64 + (x·(Mres/32))·x^T.
// ws (MiB): xh 0, xl 8 (r/p/q overlay), Th 16, Tl 24, Vt 32, Pt 40..72,
//   mtile 72, tsum 73, scale_t 74; temps in dead-Pt: Wqh 40.., Mth 48,
//   Wtvh 52, sa/sb 54.

typedef _Float16 f16;
typedef f16 f16x8 __attribute__((ext_vector_type(8)));
typedef f16 f16x4v __attribute__((ext_vector_type(4)));
typedef float f32x4 __attribute__((ext_vector_type(4)));
typedef float f32x16 __attribute__((ext_vector_type(16)));
typedef unsigned short u16;
typedef u16 u16x8 __attribute__((ext_vector_type(8)));

extern __shared__ char dsm[];  // single dynamic-LDS symbol for the whole TU

__device__ __forceinline__ void split_f32(float v, f16& h, f16& l) {
  h = (f16)v;
  l = (f16)(v - (float)h);
}

__device__ __forceinline__ void gload16(const void* g, void* l) {
  __builtin_amdgcn_global_load_lds(
      (const __attribute__((address_space(1))) void*)g,
      (__attribute__((address_space(3))) void*)l, 16, 0, 0);
}

// ---- prep: elementwise split f32 -> (h,l) f16 for x, Wq, Wk ----
__global__ __launch_bounds__(256) void k_split(
    const float* __restrict__ x, const float* __restrict__ wq,
    const float* __restrict__ wk, f16* __restrict__ xh, f16* __restrict__ xl,
    f16* __restrict__ qh, f16* __restrict__ ql, f16* __restrict__ kh,
    f16* __restrict__ kl) {
  const int z = blockIdx.z;
  const float* __restrict__ src = (z == 0) ? x : (z == 1) ? wq : wk;
  f16* __restrict__ oh = (z == 0) ? xh : (z == 1) ? qh : kh;
  f16* __restrict__ ol = (z == 0) ? xl : (z == 1) ? ql : kl;
  const int n4 = (z == 0) ? (4096 * 1024 / 4) : (1024 * 1024 / 4);
  for (int i = blockIdx.x * 256 + threadIdx.x; i < n4; i += 1024 * 256) {
    float4 f = ((const float4*)src)[i];
    f16x4v h, l;
    f16 hh, ll;
    split_f32(f.x, hh, ll); h[0] = hh; l[0] = ll;
    split_f32(f.y, hh, ll); h[1] = hh; l[1] = ll;
    split_f32(f.z, hh, ll); h[2] = hh; l[2] = ll;
    split_f32(f.w, hh, ll); h[3] = hh; l[3] = ll;
    ((f16x4v*)oh)[i] = h;
    ((f16x4v*)ol)[i] = l;
  }
}

// ---- prep: transpose+split-h Wv [a][d] f32 -> Wtvh [d][a] f16 ----
__global__ __launch_bounds__(256) void k_wsplit_v(const float* __restrict__ Wv,
                                                  f16* __restrict__ vt) {
  __shared__ float sh[64][65];
  const int kb = blockIdx.x * 64, nb = blockIdx.y * 64;
  const int t = threadIdx.x;
  const int r = t >> 2, c4 = (t & 3) * 16;
#pragma unroll
  for (int i = 0; i < 4; ++i) {
    float4 f = *(const float4*)&Wv[(size_t)(kb + r) * 1024 + nb + c4 + i * 4];
    sh[r][c4 + i * 4 + 0] = f.x;
    sh[r][c4 + i * 4 + 1] = f.y;
    sh[r][c4 + i * 4 + 2] = f.z;
    sh[r][c4 + i * 4 + 3] = f.w;
  }
  __syncthreads();
  const int n = t >> 2, ks = (t & 3) * 16;
  u16x8 h0, h1;
#pragma unroll
  for (int i = 0; i < 8; ++i) {
    h0[i] = __builtin_bit_cast(u16, (f16)sh[ks + i][n]);
    h1[i] = __builtin_bit_cast(u16, (f16)sh[ks + 8 + i][n]);
  }
  const size_t o = (size_t)(nb + n) * 1024 + kb + ks;
  *(u16x8*)&vt[o] = h0;
  *(u16x8*)&vt[o + 8] = h1;
}

// ---- prep: centered row sums ----
__global__ __launch_bounds__(256) void k_rowsums(const float* __restrict__ Wq,
                                                 const float* __restrict__ Wk,
                                                 float* __restrict__ sa,
                                                 float* __restrict__ sb) {
  const int z = blockIdx.y;
  const float* __restrict__ W = z ? Wk : Wq;
  float* __restrict__ o = z ? sb : sa;
  const int row = blockIdx.x * 4 + (threadIdx.x >> 6);
  const int lane = threadIdx.x & 63;
  const float4* src = (const float4*)(W + (size_t)row * 1024);
  float s = 0.f;
#pragma unroll
  for (int i = 0; i < 4; ++i) {
    float4 f = src[lane + 64 * i];
    s += f.x + f.y + f.z + f.w;
  }
#pragma unroll
  for (int off = 1; off < 64; off <<= 1) s += __shfl_xor(s, off, 64);
  if (lane == 0) o[row] = s - 512.0f;
}

// ---- prep: r = x*1, p = x*sa, q = x*sb ----
__global__ __launch_bounds__(256) void k_rpq(
    const float* __restrict__ x, const float* __restrict__ sa,
    const float* __restrict__ sb, float* __restrict__ rv,
    float* __restrict__ pv, float* __restrict__ qv) {
  const int row = blockIdx.x * 4 + (threadIdx.x >> 6);
  const int lane = threadIdx.x & 63;
  const float* xr = x + (size_t)row * 1024;
  float sr = 0.f, sp = 0.f, sq = 0.f;
#pragma unroll
  for (int i = 0; i < 4; ++i) {
    const int c = (lane + 64 * i) * 4;
    float4 f = *(const float4*)&xr[c];
    float4 a = *(const float4*)&sa[c];
    float4 b = *(const float4*)&sb[c];
    sr += f.x + f.y + f.z + f.w;
    sp += f.x * a.x + f.y * a.y + f.z * a.z + f.w * a.w;
    sq += f.x * b.x + f.y * b.y + f.z * b.z + f.w * b.w;
  }
#pragma unroll
  for (int off = 1; off < 64; off <<= 1) {
    sr += __shfl_xor(sr, off, 64);
    sp += __shfl_xor(sp, off, 64);
    sq += __shfl_xor(sq, off, 64);
  }
  if (lane == 0) {
    rv[row] = sr;
    pv[row] = sp;
    qv[row] = sq;
  }
}

// ---- S-residual + deferred softmax (wave-local epilogue) ----
// 256x256 tile, 2-buffer, 2-MFMA. Waves retiled: each wave owns 32 rows x
// 256 cols (acc[8] over fn). LDS: Th Tl xh (48KiB x2).
__global__ __launch_bounds__(512, 1) void k_qkt(
    const f16* __restrict__ Ah, const f16* __restrict__ Al,
    const f16* __restrict__ Bx, const float* __restrict__ rv,
    const float* __restrict__ pv, const float* __restrict__ qv,
    f16* __restrict__ Pt, float* __restrict__ mtile,
    float* __restrict__ tsum) {
  char* smem = dsm;
  constexpr int K = 1024, N = 4096, nT = 32, BUF = 49152;
  const int tid = threadIdx.x;
  const int lane = tid & 63, wv = tid >> 6;
  const int bid = blockIdx.x;
  const int wg = (bid & 7) * 32 + (bid >> 3);
  const int bx = wg >> 4, by = wg & 15;
  const int brow = bx * 256, bcol = by * 256;

  const int srow16 = lane >> 2;
  const int sslot = (lane & 3) ^ ((lane >> 3) & 3);

  const f16* bases[3] = {Ah, Al, Bx};
  const int rbase[3] = {brow, brow, bcol};

  auto stage3 = [&](int buf, int t, int half) {
    const int kt = t * 32;
    char* bb = smem + BUF * buf;
#pragma unroll
    for (int j = 0; j < 3; ++j) {
      const int g = wv * 6 + half * 3 + j;
      const int rg = g >> 4, gm = g & 15;
      gload16(
          bases[rg] + (size_t)(rbase[rg] + gm * 16 + srow16) * K + kt + 8 * sslot,
          bb + rg * 16384 + gm * 1024);
    }
  };

  f32x16 acc[8] = {};  // [fn] — wave owns rows wv*32..+31, all 256 cols
  const int l31 = lane & 31, ch0 = lane >> 5;
  const int arow = wv * 32 + l31;

  stage3(0, 0, 0);
  stage3(0, 0, 1);

  for (int t = 0; t < nT; ++t) {
    const int cur = t & 1;
    const char* bb = smem + BUF * cur;
    const bool pre = t < nT - 1;
    if (pre) {
      stage3(cur ^ 1, t + 1, 0);
      __builtin_amdgcn_sched_barrier(0);
      asm volatile("s_waitcnt vmcnt(3)" ::: "memory");
    } else {
      asm volatile("s_waitcnt vmcnt(0)" ::: "memory");
    }
    __builtin_amdgcn_sched_barrier(0);
    __builtin_amdgcn_s_barrier();
    __builtin_amdgcn_sched_barrier(0);
#pragma unroll
    for (int ks = 0; ks < 2; ++ks) {
      const int ch = ks * 2 + ch0;
      f16x8 a_h, a_l, b_h[8];
      {
        const int off = arow * 64 + 16 * (ch ^ ((arow >> 1) & 3));
        a_h = *(const f16x8*)(bb + off);
        a_l = *(const f16x8*)(bb + 16384 + off);
      }
#pragma unroll
      for (int fn = 0; fn < 8; ++fn) {
        const int r = fn * 32 + l31;
        const int off = r * 64 + 16 * (ch ^ ((r >> 1) & 3));
        b_h[fn] = *(const f16x8*)(bb + 32768 + off);
      }
      if (ks == 0 && pre) stage3(cur ^ 1, t + 1, 1);
      __builtin_amdgcn_sched_barrier(0);
      asm volatile("s_waitcnt lgkmcnt(0)" ::: "memory");
      __builtin_amdgcn_sched_barrier(0);
      __builtin_amdgcn_s_setprio(1);
#pragma unroll
      for (int fn = 0; fn < 8; ++fn) {
        acc[fn] = __builtin_amdgcn_mfma_f32_32x32x16_f16(a_h, b_h[fn], acc[fn],
                                                         0, 0, 0);
        acc[fn] = __builtin_amdgcn_mfma_f32_32x32x16_f16(a_l, b_h[fn], acc[fn],
                                                         0, 0, 0);
      }
      __builtin_amdgcn_s_setprio(0);
      __builtin_amdgcn_sched_barrier(0);
      __builtin_amdgcn_s_barrier();
    }
  }

  // ---- epilogue (wave-local): rank-1 add, row max/sum, Pt = exp(s-m) ----
  float rc[8], qc[8];
#pragma unroll
  for (int fn = 0; fn < 8; ++fn) {
    const int col = bcol + fn * 32 + l31;
    rc[fn] = rv[col];
    qc[fn] = qv[col];
  }
  const int rowbase = brow + wv * 32;
#pragma unroll
  for (int j = 0; j < 16; ++j) {
    const int rl = (j & 3) + 8 * (j >> 2) + 4 * ch0;
    const int row = rowbase + rl;
    const float rr = rv[row], pr = pv[row];
    float s[8];
    float m = -3.4e38f;
#pragma unroll
    for (int fn = 0; fn < 8; ++fn) {
      s[fn] = acc[fn][j] + 8.0f * rr * rc[fn] + (pr * rc[fn] + rr * qc[fn]) * 0.015625f;
      m = fmaxf(m, s[fn]);
    }
#pragma unroll
    for (int off = 1; off < 32; off <<= 1) m = fmaxf(m, __shfl_xor(m, off, 64));
    float sm = 0.f;
#pragma unroll
    for (int fn = 0; fn < 8; ++fn) {
      const float e = __expf(s[fn] - m);
      sm += e;
      Pt[(size_t)row * N + bcol + fn * 32 + l31] = (f16)e;
    }
#pragma unroll
    for (int off = 1; off < 32; off <<= 1) sm += __shfl_xor(sm, off, 64);
    if (l31 == 0) {
      mtile[row * 16 + by] = m;
      tsum[row * 16 + by] = sm;
    }
  }
}

// ---- scale_t[t][row] = e^{mtile-m}/sum (transposed for PV staging) ----
__global__ __launch_bounds__(256) void k_scale(const float* __restrict__ mtile,
                                               const float* __restrict__ tsum,
                                               float* __restrict__ scale_t) {
  const int row = blockIdx.x * 256 + threadIdx.x;
  float mt[16];
  float m = -3.4e38f;
#pragma unroll
  for (int t = 0; t < 16; ++t) {
    mt[t] = mtile[row * 16 + t];
    m = fmaxf(m, mt[t]);
  }
  float sum = 0.f;
#pragma unroll
  for (int t = 0; t < 16; ++t) sum += tsum[row * 16 + t] * __expf(mt[t] - m);
  const float inv = 1.0f / sum;
#pragma unroll
  for (int t = 0; t < 16; ++t)
    scale_t[t * 4096 + row] = __expf(mt[t] - m) * inv;
}

// ---- PV with folded scale: out = sum_t scale[r,t] * (Pt_chunk · V^T) ----
__global__ __launch_bounds__(512, 1) void k_pvs(const f16* __restrict__ P,
                                                const f16* __restrict__ Vt,
                                                const float* __restrict__ scale_t,
                                                float* __restrict__ out) {
  char* smem = dsm;
  constexpr int K = 4096, nT = K / 32, BUF = 16384;
  const int tid = threadIdx.x;
  const int lane = tid & 63, wv = tid >> 6;
  const int wm = wv >> 2, wn = wv & 3;
  const int bid = blockIdx.x;
  const int wg = (bid & 7) * 32 + (bid >> 3);
  const int bx = wg >> 3, by = wg & 7;
  const int brow = bx * 128, bcol = by * 128;

  const int srow16 = lane >> 2;
  const int sslot = (lane & 3) ^ ((lane >> 3) & 3);
  const int sreg = wv >> 2;
  const f16* __restrict__ sbase = sreg ? Vt : P;
  const int rbase = sreg ? bcol : brow;

  float* sc_lds = (float*)(smem + 4 * BUF);
  {
    float tmp[4];
#pragma unroll
    for (int i = 0; i < 4; ++i) {
      const int n = tid + i * 512;
      tmp[i] = scale_t[(size_t)(n >> 7) * 4096 + brow + (n & 127)];
    }
#pragma unroll
    for (int i = 0; i < 4; ++i) sc_lds[tid + i * 512] = tmp[i];
    asm volatile("s_waitcnt lgkmcnt(0)" ::: "memory");
  }

  auto stage = [&](int buf, int t) {
    const int kt = t * 32;
    char* bb = smem + BUF * buf + sreg * 8192;
#pragma unroll
    for (int j = 0; j < 2; ++j) {
      const int g = (wv & 3) * 2 + j;
      gload16(sbase + (size_t)(rbase + g * 16 + srow16) * K + kt + 8 * sslot,
              bb + g * 1024);
    }
  };

  f32x16 accp[2] = {};
  f32x16 accf[2] = {};
  const int l31 = lane & 31, ch0 = lane >> 5;
  const int arow0 = wm * 64 + l31;
  const int brow0 = wn * 32 + l31;

  stage(0, 0);
  stage(1, 1);
  stage(2, 2);

  for (int t = 0; t < nT; ++t) {
    const int rem = nT - 1 - t;
    if (rem >= 3) stage((t + 3) & 3, t + 3);
    __builtin_amdgcn_sched_barrier(0);
    if (rem >= 3) {
      asm volatile("s_waitcnt vmcnt(6)" ::: "memory");
    } else if (rem == 2) {
      asm volatile("s_waitcnt vmcnt(4)" ::: "memory");
    } else if (rem == 1) {
      asm volatile("s_waitcnt vmcnt(2)" ::: "memory");
    } else {
      asm volatile("s_waitcnt vmcnt(0)" ::: "memory");
    }
    __builtin_amdgcn_sched_barrier(0);
    __builtin_amdgcn_s_barrier();
    __builtin_amdgcn_sched_barrier(0);
    const char* bb = smem + BUF * (t & 3);
#pragma unroll
    for (int ks = 0; ks < 2; ++ks) {
      const int ch = ks * 2 + ch0;
      f16x8 a_h[2], b_h;
#pragma unroll
      for (int fm = 0; fm < 2; ++fm) {
        const int r = arow0 + fm * 32;
        a_h[fm] = *(const f16x8*)(bb + r * 64 + 16 * (ch ^ ((r >> 1) & 3)));
      }
      b_h = *(const f16x8*)(bb + 8192 + brow0 * 64 +
                            16 * (ch ^ ((brow0 >> 1) & 3)));
      __builtin_amdgcn_sched_barrier(0);
      asm volatile("s_waitcnt lgkmcnt(0)" ::: "memory");
      __builtin_amdgcn_sched_barrier(0);
      __builtin_amdgcn_s_setprio(1);
#pragma unroll
      for (int fm = 0; fm < 2; ++fm)
        accp[fm] = __builtin_amdgcn_mfma_f32_32x32x16_f16(a_h[fm], b_h,
                                                          accp[fm], 0, 0, 0);
      __builtin_amdgcn_s_setprio(0);
      __builtin_amdgcn_sched_barrier(0);
    }
    if ((t & 7) == 7) {
      const int tc = t >> 3;
#pragma unroll
      for (int fm = 0; fm < 2; ++fm)
#pragma unroll
        for (int j = 0; j < 16; ++j) {
          const int rloc =
              wm * 64 + fm * 32 + (j & 3) + 8 * (j >> 2) + 4 * ch0;
          accf[fm][j] += sc_lds[tc * 128 + rloc] * accp[fm][j];
          accp[fm][j] = 0.0f;
        }
    }
    __builtin_amdgcn_s_barrier();
  }

#pragma unroll
  for (int fm = 0; fm < 2; ++fm) {
    const int col = bcol + wn * 32 + l31;
#pragma unroll
    for (int j = 0; j < 16; ++j) {
      const int row =
          brow + wm * 64 + fm * 32 + (j & 3) + 8 * (j >> 2) + 4 * ch0;
      out[(size_t)row * 1024 + col] = accf[fm][j];
    }
  }
}

// ---- depth-3 pipelined BT-GEMM (Vt): C = A . B^T, f16 out ----
template <int K, int NBY>
__global__ __launch_bounds__(512, 1) void pipe_bt(const f16* __restrict__ A,
                                                  const f16* __restrict__ B,
                                                  f16* __restrict__ outh,
                                                  int ldo) {
  char* smem = dsm;
  constexpr int nT = K / 32, BUF = 16384;
  const int tid = threadIdx.x;
  const int lane = tid & 63, wv = tid >> 6;
  const int wm = wv >> 2, wn = wv & 3;
  const int bid = blockIdx.x;
  const int wg = (bid & 7) * 32 + (bid >> 3);
  const int bx = wg / NBY, by = wg % NBY;
  const int brow = bx * 128, bcol = by * 128;

  const int srow16 = lane >> 2;
  const int sslot = (lane & 3) ^ ((lane >> 3) & 3);
  const int sreg = wv >> 2;
  const f16* __restrict__ sbase = sreg ? B : A;
  const int rbase = sreg ? bcol : brow;

  auto stage = [&](int buf, int t) {
    const int kt = t * 32;
    char* bb = smem + BUF * buf + sreg * 8192;
#pragma unroll
    for (int j = 0; j < 2; ++j) {
      const int g = (wv & 3) * 2 + j;
      gload16(sbase + (size_t)(rbase + g * 16 + srow16) * K + kt + 8 * sslot,
              bb + g * 1024);
    }
  };

  f32x16 acc[2] = {};
  const int l31 = lane & 31, ch0 = lane >> 5;
  const int arow0 = wm * 64 + l31;
  const int brow0 = wn * 32 + l31;

  stage(0, 0);
  stage(1, 1);
  stage(2, 2);

  for (int t = 0; t < nT; ++t) {
    const int rem = nT - 1 - t;
    if (rem >= 3) stage((t + 3) & 3, t + 3);
    __builtin_amdgcn_sched_barrier(0);
    if (rem >= 3) {
      asm volatile("s_waitcnt vmcnt(6)" ::: "memory");
    } else if (rem == 2) {
      asm volatile("s_waitcnt vmcnt(4)" ::: "memory");
    } else if (rem == 1) {
      asm volatile("s_waitcnt vmcnt(2)" ::: "memory");
    } else {
      asm volatile("s_waitcnt vmcnt(0)" ::: "memory");
    }
    __builtin_amdgcn_sched_barrier(0);
    __builtin_amdgcn_s_barrier();
    __builtin_amdgcn_sched_barrier(0);
    const char* bb = smem + BUF * (t & 3);
#pragma unroll
    for (int ks = 0; ks < 2; ++ks) {
      const int ch = ks * 2 + ch0;
      f16x8 a_h[2], b_h;
#pragma unroll
      for (int fm = 0; fm < 2; ++fm) {
        const int r = arow0 + fm * 32;
        a_h[fm] = *(const f16x8*)(bb + r * 64 + 16 * (ch ^ ((r >> 1) & 3)));
      }
      b_h = *(const f16x8*)(bb + 8192 + brow0 * 64 +
                            16 * (ch ^ ((brow0 >> 1) & 3)));
      __builtin_amdgcn_sched_barrier(0);
      asm volatile("s_waitcnt lgkmcnt(0)" ::: "memory");
      __builtin_amdgcn_sched_barrier(0);
      __builtin_amdgcn_s_setprio(1);
#pragma unroll
      for (int fm = 0; fm < 2; ++fm)
        acc[fm] = __builtin_amdgcn_mfma_f32_32x32x16_f16(a_h[fm], b_h, acc[fm],
                                                         0, 0, 0);
      __builtin_amdgcn_s_setprio(0);
      __builtin_amdgcn_sched_barrier(0);
    }
    __builtin_amdgcn_s_barrier();
  }

#pragma unroll
  for (int fm = 0; fm < 2; ++fm) {
    const int col = bcol + wn * 32 + l31;
#pragma unroll
    for (int j = 0; j < 16; ++j) {
      const int row =
          brow + wm * 64 + fm * 32 + (j & 3) + 8 * (j >> 2) + 4 * ch0;
      outh[(size_t)row * ldo + col] = (f16)acc[fm][j];
    }
  }
}

// ---- generic BT-GEMM (m97-style) ----
// NM: 3 = AhBh+AhBl+AlBh; 2 = AhBh+AlBh (no Bl).
// OUT: 1 split f16; 4 rank1-subtract then f16 h-only.
template <int NM, int OUT>
__global__ __launch_bounds__(256) void gemm_bt(
    const f16* __restrict__ A, const f16* __restrict__ Al,
    const f16* __restrict__ B, const f16* __restrict__ Bl, int K,
    f16* __restrict__ oh, f16* __restrict__ ol, int ldo, float scale,
    const float* __restrict__ sav, const float* __restrict__ sbv) {
  f16* smem = (f16*)dsm;
  f16* tAh = smem;
  f16* tBh = smem + 8192;
  f16* tAl = smem + 16384;
  f16* tBl = smem + 24576;

  const int tid = threadIdx.x;
  const int lane = tid & 63, wid = tid >> 6;
  const int wr = wid >> 1, wc = wid & 1;
  const int brow = blockIdx.x * 128, bcol = blockIdx.y * 128;
  const int ar = lane & 15, k0 = (lane >> 4) * 8;
  const int crow = lane >> 3, ccol = (lane & 7) * 8;

  f32x4 acc[4][4] = {};
  const size_t aoff = (size_t)crow * K + ccol;

  for (int kt = 0; kt < K; kt += 64) {
    const f16* Ab = A + (size_t)brow * K + kt;
    const f16* Bb = B + (size_t)bcol * K + kt;
#pragma unroll
    for (int cc = 0; cc < 4; ++cc) {
      const int c = wid * 4 + cc;
      const size_t co = (size_t)c * 8 * K + aoff;
      gload16(Ab + co, tAh + c * 512);
      gload16(Bb + co, tBh + c * 512);
      if constexpr (NM >= 2) gload16(Al + (size_t)brow * K + kt + co, tAl + c * 512);
      if constexpr (NM == 3) gload16(Bl + (size_t)bcol * K + kt + co, tBl + c * 512);
    }
    __syncthreads();
#pragma unroll
    for (int ks = 0; ks < 2; ++ks) {
      f16x8 ah[4], bh[4], alv[4], blv[4];
#pragma unroll
      for (int m = 0; m < 4; ++m) {
        ah[m] = *(const f16x8*)&tAh[(wr * 64 + m * 16 + ar) * 64 + ks * 32 + k0];
        bh[m] = *(const f16x8*)&tBh[(wc * 64 + m * 16 + ar) * 64 + ks * 32 + k0];
        if constexpr (NM >= 2)
          alv[m] = *(const f16x8*)&tAl[(wr * 64 + m * 16 + ar) * 64 + ks * 32 + k0];
        if constexpr (NM == 3)
          blv[m] = *(const f16x8*)&tBl[(wc * 64 + m * 16 + ar) * 64 + ks * 32 + k0];
      }
#pragma unroll
      for (int m = 0; m < 4; ++m)
#pragma unroll
        for (int n = 0; n < 4; ++n) {
          acc[m][n] = __builtin_amdgcn_mfma_f32_16x16x32_f16(ah[m], bh[n], acc[m][n], 0, 0, 0);
          if constexpr (NM >= 2)
            acc[m][n] = __builtin_amdgcn_mfma_f32_16x16x32_f16(alv[m], bh[n], acc[m][n], 0, 0, 0);
          if constexpr (NM == 3)
            acc[m][n] = __builtin_amdgcn_mfma_f32_16x16x32_f16(ah[m], blv[n], acc[m][n], 0, 0, 0);
        }
    }
    __syncthreads();
  }

#pragma unroll
  for (int m = 0; m < 4; ++m)
#pragma unroll
    for (int n = 0; n < 4; ++n)
#pragma unroll
      for (int j = 0; j < 4; ++j) {
        const int row = brow + wr * 64 + m * 16 + (lane >> 4) * 4 + j;
        const int col = bcol + wc * 64 + n * 16 + ar;
        const size_t idx = (size_t)row * ldo + col;
        if constexpr (OUT == 1) {
          f16 h, l;
          split_f32(acc[m][n][j] * scale, h, l);
          oh[idx] = h;
          ol[idx] = l;
        } else {  // OUT == 4: rank1-subtract, h only
          const float v =
              (acc[m][n][j] - 256.0f - 0.5f * sav[col] - 0.5f * sbv[row]) * scale;
          oh[idx] = (f16)v;
        }
      }
}

extern "C" void kernel_launch(void* const* d_in, const int* in_sizes, int n_in,
                              void* d_out, int out_size, void* d_ws,
                              size_t ws_size, hipStream_t stream) {
  const float* x = (const float*)d_in[0];
  const float* Wq = (const float*)d_in[1];
  const float* Wk = (const float*)d_in[2];
  const float* Wv = (const float*)d_in[3];
  float* out = (float*)d_out;
  char* ws = (char*)d_ws;
  const size_t MiB = 1u << 20;
  f16* xh = (f16*)(ws + 0 * MiB);
  f16* xl = (f16*)(ws + 8 * MiB);
  f16* Th = (f16*)(ws + 16 * MiB);
  f16* Tl = (f16*)(ws + 24 * MiB);
  f16* Vt = (f16*)(ws + 32 * MiB);
  f16* Pt = (f16*)(ws + 40 * MiB);         // 32 MiB
  float* mtile = (float*)(ws + 72 * MiB);  // 256 KiB
  float* tsum = (float*)(ws + 73 * MiB);   // 256 KiB
  float* scale_t = (float*)(ws + 74 * MiB);
  f16* Wqh = (f16*)(ws + 40 * MiB);        // dead-Pt temps (pre-k_qkt)
  f16* Wql = (f16*)(ws + 42 * MiB);
  f16* Wkh = (f16*)(ws + 44 * MiB);
  f16* Wkl = (f16*)(ws + 46 * MiB);
  f16* Mth = (f16*)(ws + 48 * MiB);
  f16* Wtvh = (f16*)(ws + 52 * MiB);
  float* sa = (float*)(ws + 54 * MiB);
  float* sb = (float*)(ws + 54 * MiB + 65536);
  float* rv = (float*)(ws + 8 * MiB);
  float* pv = (float*)(ws + 8 * MiB + 65536);
  float* qv = (float*)(ws + 8 * MiB + 131072);

  (void)hipFuncSetAttribute((const void*)k_qkt,
                            hipFuncAttributeMaxDynamicSharedMemorySize, 98304);
  (void)hipFuncSetAttribute((const void*)k_pvs,
                            hipFuncAttributeMaxDynamicSharedMemorySize, 73728);
  (void)hipFuncSetAttribute((const void*)pipe_bt<1024, 32>,
                            hipFuncAttributeMaxDynamicSharedMemorySize, 65536);

  k_split<<<dim3(1024, 1, 3), 256, 0, stream>>>(x, Wq, Wk, xh, xl, Wqh, Wql,
                                                Wkh, Wkl);
  k_wsplit_v<<<dim3(16, 16), 256, 0, stream>>>(Wv, Wtvh);
  k_rowsums<<<dim3(256, 2), 256, 0, stream>>>(Wq, Wk, sa, sb);
  gemm_bt<3, 4><<<dim3(8, 8), 256, 65536, stream>>>(
      Wkh, Wkl, Wqh, Wql, 1024, Mth, nullptr, 1024, 0.03125f, sa, sb);
  gemm_bt<2, 1><<<dim3(32, 8), 256, 49152, stream>>>(
      xh, xl, Mth, nullptr, 1024, Th, Tl, 1024, 1.0f, nullptr, nullptr);
  pipe_bt<1024, 32><<<dim3(256), 512, 65536, stream>>>(Wtvh, xh, Vt, 4096);
  k_rpq<<<dim3(1024), 256, 0, stream>>>(x, sa, sb, rv, pv, qv);
  k_qkt<<<dim3(256), 512, 98304, stream>>>(Th, Tl, xh, rv, pv, qv, Pt, mtile,
                                           tsum);
  k_scale<<<dim3(16), 256, 0, stream>>>(mtile, tsum, scale_t);
  k_pvs<<<dim3(256), 512, 73728, stream>>>(Pt, Vt, scale_t, out);
}

// Round 16
// 243.712 us; speedup vs baseline: 1.0818x; 1.0117x over previous
//
#include <hip/hip_runtime.h>

// SelfAttention: out = softmax((xWq)(xWk)^T/32) @ (xWv), f32, S=4096, D=1024.
// R16: R15 + (a) k_qkt barrier diet: ks0-end barrier removed (no WAR within a
// tile: ks1 reads the same buffer; buf-overwrite is fenced by the ks1-end
// barrier since stage(t+2) issues after it) -> ks1 ds_reads overlap ks0 MFMA;
// (b) k_scale folded into k_pvs preamble (per-block scale slice from
// mtile/tsum into LDS) - one fewer launch.
// scores = 8rr^T + (pr^T+rq^T)/64 + (x·(Mres/32))·x^T; deferred per-tile
// softmax: Pt = exp(s-m_tile) f16 + {mtile,tsum}; PV folds scale per-chunk.
// ws (MiB): xh 0, xl 8 (r/p/q overlay), Th 16, Tl 24, Vt 32, Pt 40..72,
//   mtile 72, tsum 73; temps in dead-Pt: Wqh 40.., Mth 48, Wtvh 52, sa/sb 54.

typedef _Float16 f16;
typedef f16 f16x8 __attribute__((ext_vector_type(8)));
typedef f16 f16x4v __attribute__((ext_vector_type(4)));
typedef float f32x4 __attribute__((ext_vector_type(4)));
typedef float f32x16 __attribute__((ext_vector_type(16)));
typedef unsigned short u16;
typedef u16 u16x8 __attribute__((ext_vector_type(8)));

extern __shared__ char dsm[];  // single dynamic-LDS symbol for the whole TU

__device__ __forceinline__ void split_f32(float v, f16& h, f16& l) {
  h = (f16)v;
  l = (f16)(v - (float)h);
}

__device__ __forceinline__ void gload16(const void* g, void* l) {
  __builtin_amdgcn_global_load_lds(
      (const __attribute__((address_space(1))) void*)g,
      (__attribute__((address_space(3))) void*)l, 16, 0, 0);
}

// ---- prep: elementwise split f32 -> (h,l) f16 for x, Wq, Wk ----
__global__ __launch_bounds__(256) void k_split(
    const float* __restrict__ x, const float* __restrict__ wq,
    const float* __restrict__ wk, f16* __restrict__ xh, f16* __restrict__ xl,
    f16* __restrict__ qh, f16* __restrict__ ql, f16* __restrict__ kh,
    f16* __restrict__ kl) {
  const int z = blockIdx.z;
  const float* __restrict__ src = (z == 0) ? x : (z == 1) ? wq : wk;
  f16* __restrict__ oh = (z == 0) ? xh : (z == 1) ? qh : kh;
  f16* __restrict__ ol = (z == 0) ? xl : (z == 1) ? ql : kl;
  const int n4 = (z == 0) ? (4096 * 1024 / 4) : (1024 * 1024 / 4);
  for (int i = blockIdx.x * 256 + threadIdx.x; i < n4; i += 1024 * 256) {
    float4 f = ((const float4*)src)[i];
    f16x4v h, l;
    f16 hh, ll;
    split_f32(f.x, hh, ll); h[0] = hh; l[0] = ll;
    split_f32(f.y, hh, ll); h[1] = hh; l[1] = ll;
    split_f32(f.z, hh, ll); h[2] = hh; l[2] = ll;
    split_f32(f.w, hh, ll); h[3] = hh; l[3] = ll;
    ((f16x4v*)oh)[i] = h;
    ((f16x4v*)ol)[i] = l;
  }
}

// ---- prep: transpose+split-h Wv [a][d] f32 -> Wtvh [d][a] f16 ----
__global__ __launch_bounds__(256) void k_wsplit_v(const float* __restrict__ Wv,
                                                  f16* __restrict__ vt) {
  __shared__ float sh[64][65];
  const int kb = blockIdx.x * 64, nb = blockIdx.y * 64;
  const int t = threadIdx.x;
  const int r = t >> 2, c4 = (t & 3) * 16;
#pragma unroll
  for (int i = 0; i < 4; ++i) {
    float4 f = *(const float4*)&Wv[(size_t)(kb + r) * 1024 + nb + c4 + i * 4];
    sh[r][c4 + i * 4 + 0] = f.x;
    sh[r][c4 + i * 4 + 1] = f.y;
    sh[r][c4 + i * 4 + 2] = f.z;
    sh[r][c4 + i * 4 + 3] = f.w;
  }
  __syncthreads();
  const int n = t >> 2, ks = (t & 3) * 16;
  u16x8 h0, h1;
#pragma unroll
  for (int i = 0; i < 8; ++i) {
    h0[i] = __builtin_bit_cast(u16, (f16)sh[ks + i][n]);
    h1[i] = __builtin_bit_cast(u16, (f16)sh[ks + 8 + i][n]);
  }
  const size_t o = (size_t)(nb + n) * 1024 + kb + ks;
  *(u16x8*)&vt[o] = h0;
  *(u16x8*)&vt[o + 8] = h1;
}

// ---- prep: centered row sums ----
__global__ __launch_bounds__(256) void k_rowsums(const float* __restrict__ Wq,
                                                 const float* __restrict__ Wk,
                                                 float* __restrict__ sa,
                                                 float* __restrict__ sb) {
  const int z = blockIdx.y;
  const float* __restrict__ W = z ? Wk : Wq;
  float* __restrict__ o = z ? sb : sa;
  const int row = blockIdx.x * 4 + (threadIdx.x >> 6);
  const int lane = threadIdx.x & 63;
  const float4* src = (const float4*)(W + (size_t)row * 1024);
  float s = 0.f;
#pragma unroll
  for (int i = 0; i < 4; ++i) {
    float4 f = src[lane + 64 * i];
    s += f.x + f.y + f.z + f.w;
  }
#pragma unroll
  for (int off = 1; off < 64; off <<= 1) s += __shfl_xor(s, off, 64);
  if (lane == 0) o[row] = s - 512.0f;
}

// ---- prep: r = x*1, p = x*sa, q = x*sb ----
__global__ __launch_bounds__(256) void k_rpq(
    const float* __restrict__ x, const float* __restrict__ sa,
    const float* __restrict__ sb, float* __restrict__ rv,
    float* __restrict__ pv, float* __restrict__ qv) {
  const int row = blockIdx.x * 4 + (threadIdx.x >> 6);
  const int lane = threadIdx.x & 63;
  const float* xr = x + (size_t)row * 1024;
  float sr = 0.f, sp = 0.f, sq = 0.f;
#pragma unroll
  for (int i = 0; i < 4; ++i) {
    const int c = (lane + 64 * i) * 4;
    float4 f = *(const float4*)&xr[c];
    float4 a = *(const float4*)&sa[c];
    float4 b = *(const float4*)&sb[c];
    sr += f.x + f.y + f.z + f.w;
    sp += f.x * a.x + f.y * a.y + f.z * a.z + f.w * a.w;
    sq += f.x * b.x + f.y * b.y + f.z * b.z + f.w * b.w;
  }
#pragma unroll
  for (int off = 1; off < 64; off <<= 1) {
    sr += __shfl_xor(sr, off, 64);
    sp += __shfl_xor(sp, off, 64);
    sq += __shfl_xor(sq, off, 64);
  }
  if (lane == 0) {
    rv[row] = sr;
    pv[row] = sp;
    qv[row] = sq;
  }
}

// ---- S-residual + deferred softmax (wave-local epilogue) ----
// 256x256 tile, 2-buffer, 2-MFMA, 2 barriers/tile. Waves: 32 rows x 256 cols.
__global__ __launch_bounds__(512, 1) void k_qkt(
    const f16* __restrict__ Ah, const f16* __restrict__ Al,
    const f16* __restrict__ Bx, const float* __restrict__ rv,
    const float* __restrict__ pv, const float* __restrict__ qv,
    f16* __restrict__ Pt, float* __restrict__ mtile,
    float* __restrict__ tsum) {
  char* smem = dsm;
  constexpr int K = 1024, N = 4096, nT = 32, BUF = 49152;
  const int tid = threadIdx.x;
  const int lane = tid & 63, wv = tid >> 6;
  const int bid = blockIdx.x;
  const int wg = (bid & 7) * 32 + (bid >> 3);
  const int bx = wg >> 4, by = wg & 15;
  const int brow = bx * 256, bcol = by * 256;

  const int srow16 = lane >> 2;
  const int sslot = (lane & 3) ^ ((lane >> 3) & 3);

  const f16* bases[3] = {Ah, Al, Bx};
  const int rbase[3] = {brow, brow, bcol};

  auto stage3 = [&](int buf, int t, int half) {
    const int kt = t * 32;
    char* bb = smem + BUF * buf;
#pragma unroll
    for (int j = 0; j < 3; ++j) {
      const int g = wv * 6 + half * 3 + j;
      const int rg = g >> 4, gm = g & 15;
      gload16(
          bases[rg] + (size_t)(rbase[rg] + gm * 16 + srow16) * K + kt + 8 * sslot,
          bb + rg * 16384 + gm * 1024);
    }
  };

  f32x16 acc[8] = {};  // [fn] — wave owns rows wv*32..+31, all 256 cols
  const int l31 = lane & 31, ch0 = lane >> 5;
  const int arow = wv * 32 + l31;

  stage3(0, 0, 0);
  stage3(0, 0, 1);

  for (int t = 0; t < nT; ++t) {
    const int cur = t & 1;
    const char* bb = smem + BUF * cur;
    const bool pre = t < nT - 1;
    if (pre) {
      stage3(cur ^ 1, t + 1, 0);
      __builtin_amdgcn_sched_barrier(0);
      asm volatile("s_waitcnt vmcnt(3)" ::: "memory");
    } else {
      asm volatile("s_waitcnt vmcnt(0)" ::: "memory");
    }
    __builtin_amdgcn_sched_barrier(0);
    __builtin_amdgcn_s_barrier();  // RAW: tile t staging landed (all waves)
    __builtin_amdgcn_sched_barrier(0);

    // ---- ks0 ----
    f16x8 a_h0, a_l0, b_h0[8];
    {
      const int ch = ch0;
      const int offA = arow * 64 + 16 * (ch ^ ((arow >> 1) & 3));
      a_h0 = *(const f16x8*)(bb + offA);
      a_l0 = *(const f16x8*)(bb + 16384 + offA);
#pragma unroll
      for (int fn = 0; fn < 8; ++fn) {
        const int r = fn * 32 + l31;
        const int off = r * 64 + 16 * (ch ^ ((r >> 1) & 3));
        b_h0[fn] = *(const f16x8*)(bb + 32768 + off);
      }
    }
    if (pre) stage3(cur ^ 1, t + 1, 1);
    asm volatile("s_waitcnt lgkmcnt(0)" ::: "memory");
    __builtin_amdgcn_sched_barrier(0);
    __builtin_amdgcn_s_setprio(1);
#pragma unroll
    for (int fn = 0; fn < 8; ++fn) {
      acc[fn] = __builtin_amdgcn_mfma_f32_32x32x16_f16(a_h0, b_h0[fn], acc[fn],
                                                       0, 0, 0);
      acc[fn] = __builtin_amdgcn_mfma_f32_32x32x16_f16(a_l0, b_h0[fn], acc[fn],
                                                       0, 0, 0);
    }
    __builtin_amdgcn_s_setprio(0);

    // ---- ks1 (no barrier: same buffer, no WAR; reads may hoist into ks0) ----
    f16x8 a_h1, a_l1, b_h1[8];
    {
      const int ch = 2 + ch0;
      const int offA = arow * 64 + 16 * (ch ^ ((arow >> 1) & 3));
      a_h1 = *(const f16x8*)(bb + offA);
      a_l1 = *(const f16x8*)(bb + 16384 + offA);
#pragma unroll
      for (int fn = 0; fn < 8; ++fn) {
        const int r = fn * 32 + l31;
        const int off = r * 64 + 16 * (ch ^ ((r >> 1) & 3));
        b_h1[fn] = *(const f16x8*)(bb + 32768 + off);
      }
    }
    asm volatile("s_waitcnt lgkmcnt(0)" ::: "memory");
    __builtin_amdgcn_sched_barrier(0);
    __builtin_amdgcn_s_setprio(1);
#pragma unroll
    for (int fn = 0; fn < 8; ++fn) {
      acc[fn] = __builtin_amdgcn_mfma_f32_32x32x16_f16(a_h1, b_h1[fn], acc[fn],
                                                       0, 0, 0);
      acc[fn] = __builtin_amdgcn_mfma_f32_32x32x16_f16(a_l1, b_h1[fn], acc[fn],
                                                       0, 0, 0);
    }
    __builtin_amdgcn_s_setprio(0);
    __builtin_amdgcn_sched_barrier(0);
    __builtin_amdgcn_s_barrier();  // WAR: buf cur reads drained before t+2 stage
  }

  // ---- epilogue (wave-local): rank-1 add, row max/sum, Pt = exp(s-m) ----
  float rc[8], qc[8];
#pragma unroll
  for (int fn = 0; fn < 8; ++fn) {
    const int col = bcol + fn * 32 + l31;
    rc[fn] = rv[col];
    qc[fn] = qv[col];
  }
  const int rowbase = brow + wv * 32;
#pragma unroll
  for (int j = 0; j < 16; ++j) {
    const int rl = (j & 3) + 8 * (j >> 2) + 4 * ch0;
    const int row = rowbase + rl;
    const float rr = rv[row], pr = pv[row];
    float s[8];
    float m = -3.4e38f;
#pragma unroll
    for (int fn = 0; fn < 8; ++fn) {
      s[fn] = acc[fn][j] + 8.0f * rr * rc[fn] + (pr * rc[fn] + rr * qc[fn]) * 0.015625f;
      m = fmaxf(m, s[fn]);
    }
#pragma unroll
    for (int off = 1; off < 32; off <<= 1) m = fmaxf(m, __shfl_xor(m, off, 64));
    float sm = 0.f;
#pragma unroll
    for (int fn = 0; fn < 8; ++fn) {
      const float e = __expf(s[fn] - m);
      sm += e;
      Pt[(size_t)row * N + bcol + fn * 32 + l31] = (f16)e;
    }
#pragma unroll
    for (int off = 1; off < 32; off <<= 1) sm += __shfl_xor(sm, off, 64);
    if (l31 == 0) {
      mtile[row * 16 + by] = m;
      tsum[row * 16 + by] = sm;
    }
  }
}

// ---- PV with folded scale: out = sum_t scale[r,t] * (Pt_chunk · V^T) ----
// scale computed in-kernel from mtile/tsum (k_scale folded in).
__global__ __launch_bounds__(512, 1) void k_pvs(const f16* __restrict__ P,
                                                const f16* __restrict__ Vt,
                                                const float* __restrict__ mtile,
                                                const float* __restrict__ tsum,
                                                float* __restrict__ out) {
  char* smem = dsm;
  constexpr int K = 4096, nT = K / 32, BUF = 16384;
  const int tid = threadIdx.x;
  const int lane = tid & 63, wv = tid >> 6;
  const int wm = wv >> 2, wn = wv & 3;
  const int bid = blockIdx.x;
  const int wg = (bid & 7) * 32 + (bid >> 3);
  const int bx = wg >> 3, by = wg & 7;
  const int brow = bx * 128, bcol = by * 128;

  const int srow16 = lane >> 2;
  const int sslot = (lane & 3) ^ ((lane >> 3) & 3);
  const int sreg = wv >> 2;
  const f16* __restrict__ sbase = sreg ? Vt : P;
  const int rbase = sreg ? bcol : brow;

  // ---- preamble: per-block scale slice [16][128] from mtile/tsum ----
  float* sc_lds = (float*)(smem + 4 * BUF);
  if (tid < 128) {
    const int row = brow + tid;
    float mt[16], ts[16];
    float m = -3.4e38f;
#pragma unroll
    for (int t4 = 0; t4 < 4; ++t4) {
      float4 v = *(const float4*)&mtile[row * 16 + t4 * 4];
      float4 w = *(const float4*)&tsum[row * 16 + t4 * 4];
      mt[t4 * 4 + 0] = v.x; mt[t4 * 4 + 1] = v.y;
      mt[t4 * 4 + 2] = v.z; mt[t4 * 4 + 3] = v.w;
      ts[t4 * 4 + 0] = w.x; ts[t4 * 4 + 1] = w.y;
      ts[t4 * 4 + 2] = w.z; ts[t4 * 4 + 3] = w.w;
      m = fmaxf(m, fmaxf(fmaxf(v.x, v.y), fmaxf(v.z, v.w)));
    }
    float sum = 0.f;
#pragma unroll
    for (int t = 0; t < 16; ++t) sum += ts[t] * __expf(mt[t] - m);
    const float inv = 1.0f / sum;
#pragma unroll
    for (int t = 0; t < 16; ++t)
      sc_lds[t * 128 + tid] = __expf(mt[t] - m) * inv;
  }
  __syncthreads();

  auto stage = [&](int buf, int t) {
    const int kt = t * 32;
    char* bb = smem + BUF * buf + sreg * 8192;
#pragma unroll
    for (int j = 0; j < 2; ++j) {
      const int g = (wv & 3) * 2 + j;
      gload16(sbase + (size_t)(rbase + g * 16 + srow16) * K + kt + 8 * sslot,
              bb + g * 1024);
    }
  };

  f32x16 accp[2] = {};
  f32x16 accf[2] = {};
  const int l31 = lane & 31, ch0 = lane >> 5;
  const int arow0 = wm * 64 + l31;
  const int brow0 = wn * 32 + l31;

  stage(0, 0);
  stage(1, 1);
  stage(2, 2);

  for (int t = 0; t < nT; ++t) {
    const int rem = nT - 1 - t;
    if (rem >= 3) stage((t + 3) & 3, t + 3);
    __builtin_amdgcn_sched_barrier(0);
    if (rem >= 3) {
      asm volatile("s_waitcnt vmcnt(6)" ::: "memory");
    } else if (rem == 2) {
      asm volatile("s_waitcnt vmcnt(4)" ::: "memory");
    } else if (rem == 1) {
      asm volatile("s_waitcnt vmcnt(2)" ::: "memory");
    } else {
      asm volatile("s_waitcnt vmcnt(0)" ::: "memory");
    }
    __builtin_amdgcn_sched_barrier(0);
    __builtin_amdgcn_s_barrier();
    __builtin_amdgcn_sched_barrier(0);
    const char* bb = smem + BUF * (t & 3);
#pragma unroll
    for (int ks = 0; ks < 2; ++ks) {
      const int ch = ks * 2 + ch0;
      f16x8 a_h[2], b_h;
#pragma unroll
      for (int fm = 0; fm < 2; ++fm) {
        const int r = arow0 + fm * 32;
        a_h[fm] = *(const f16x8*)(bb + r * 64 + 16 * (ch ^ ((r >> 1) & 3)));
      }
      b_h = *(const f16x8*)(bb + 8192 + brow0 * 64 +
                            16 * (ch ^ ((brow0 >> 1) & 3)));
      __builtin_amdgcn_sched_barrier(0);
      asm volatile("s_waitcnt lgkmcnt(0)" ::: "memory");
      __builtin_amdgcn_sched_barrier(0);
      __builtin_amdgcn_s_setprio(1);
#pragma unroll
      for (int fm = 0; fm < 2; ++fm)
        accp[fm] = __builtin_amdgcn_mfma_f32_32x32x16_f16(a_h[fm], b_h,
                                                          accp[fm], 0, 0, 0);
      __builtin_amdgcn_s_setprio(0);
      __builtin_amdgcn_sched_barrier(0);
    }
    if ((t & 7) == 7) {
      const int tc = t >> 3;
#pragma unroll
      for (int fm = 0; fm < 2; ++fm)
#pragma unroll
        for (int j = 0; j < 16; ++j) {
          const int rloc =
              wm * 64 + fm * 32 + (j & 3) + 8 * (j >> 2) + 4 * ch0;
          accf[fm][j] += sc_lds[tc * 128 + rloc] * accp[fm][j];
          accp[fm][j] = 0.0f;
        }
    }
    __builtin_amdgcn_s_barrier();
  }

#pragma unroll
  for (int fm = 0; fm < 2; ++fm) {
    const int col = bcol + wn * 32 + l31;
#pragma unroll
    for (int j = 0; j < 16; ++j) {
      const int row =
          brow + wm * 64 + fm * 32 + (j & 3) + 8 * (j >> 2) + 4 * ch0;
      out[(size_t)row * 1024 + col] = accf[fm][j];
    }
  }
}

// ---- depth-3 pipelined BT-GEMM (Vt): C = A . B^T, f16 out ----
template <int K, int NBY>
__global__ __launch_bounds__(512, 1) void pipe_bt(const f16* __restrict__ A,
                                                  const f16* __restrict__ B,
                                                  f16* __restrict__ outh,
                                                  int ldo) {
  char* smem = dsm;
  constexpr int nT = K / 32, BUF = 16384;
  const int tid = threadIdx.x;
  const int lane = tid & 63, wv = tid >> 6;
  const int wm = wv >> 2, wn = wv & 3;
  const int bid = blockIdx.x;
  const int wg = (bid & 7) * 32 + (bid >> 3);
  const int bx = wg / NBY, by = wg % NBY;
  const int brow = bx * 128, bcol = by * 128;

  const int srow16 = lane >> 2;
  const int sslot = (lane & 3) ^ ((lane >> 3) & 3);
  const int sreg = wv >> 2;
  const f16* __restrict__ sbase = sreg ? B : A;
  const int rbase = sreg ? bcol : brow;

  auto stage = [&](int buf, int t) {
    const int kt = t * 32;
    char* bb = smem + BUF * buf + sreg * 8192;
#pragma unroll
    for (int j = 0; j < 2; ++j) {
      const int g = (wv & 3) * 2 + j;
      gload16(sbase + (size_t)(rbase + g * 16 + srow16) * K + kt + 8 * sslot,
              bb + g * 1024);
    }
  };

  f32x16 acc[2] = {};
  const int l31 = lane & 31, ch0 = lane >> 5;
  const int arow0 = wm * 64 + l31;
  const int brow0 = wn * 32 + l31;

  stage(0, 0);
  stage(1, 1);
  stage(2, 2);

  for (int t = 0; t < nT; ++t) {
    const int rem = nT - 1 - t;
    if (rem >= 3) stage((t + 3) & 3, t + 3);
    __builtin_amdgcn_sched_barrier(0);
    if (rem >= 3) {
      asm volatile("s_waitcnt vmcnt(6)" ::: "memory");
    } else if (rem == 2) {
      asm volatile("s_waitcnt vmcnt(4)" ::: "memory");
    } else if (rem == 1) {
      asm volatile("s_waitcnt vmcnt(2)" ::: "memory");
    } else {
      asm volatile("s_waitcnt vmcnt(0)" ::: "memory");
    }
    __builtin_amdgcn_sched_barrier(0);
    __builtin_amdgcn_s_barrier();
    __builtin_amdgcn_sched_barrier(0);
    const char* bb = smem + BUF * (t & 3);
#pragma unroll
    for (int ks = 0; ks < 2; ++ks) {
      const int ch = ks * 2 + ch0;
      f16x8 a_h[2], b_h;
#pragma unroll
      for (int fm = 0; fm < 2; ++fm) {
        const int r = arow0 + fm * 32;
        a_h[fm] = *(const f16x8*)(bb + r * 64 + 16 * (ch ^ ((r >> 1) & 3)));
      }
      b_h = *(const f16x8*)(bb + 8192 + brow0 * 64 +
                            16 * (ch ^ ((brow0 >> 1) & 3)));
      __builtin_amdgcn_sched_barrier(0);
      asm volatile("s_waitcnt lgkmcnt(0)" ::: "memory");
      __builtin_amdgcn_sched_barrier(0);
      __builtin_amdgcn_s_setprio(1);
#pragma unroll
      for (int fm = 0; fm < 2; ++fm)
        acc[fm] = __builtin_amdgcn_mfma_f32_32x32x16_f16(a_h[fm], b_h, acc[fm],
                                                         0, 0, 0);
      __builtin_amdgcn_s_setprio(0);
      __builtin_amdgcn_sched_barrier(0);
    }
    __builtin_amdgcn_s_barrier();
  }

#pragma unroll
  for (int fm = 0; fm < 2; ++fm) {
    const int col = bcol + wn * 32 + l31;
#pragma unroll
    for (int j = 0; j < 16; ++j) {
      const int row =
          brow + wm * 64 + fm * 32 + (j & 3) + 8 * (j >> 2) + 4 * ch0;
      outh[(size_t)row * ldo + col] = (f16)acc[fm][j];
    }
  }
}

// ---- generic BT-GEMM (m97-style) ----
// NM: 3 = AhBh+AhBl+AlBh; 2 = AhBh+AlBh (no Bl).
// OUT: 1 split f16; 4 rank1-subtract then f16 h-only.
template <int NM, int OUT>
__global__ __launch_bounds__(256) void gemm_bt(
    const f16* __restrict__ A, const f16* __restrict__ Al,
    const f16* __restrict__ B, const f16* __restrict__ Bl, int K,
    f16* __restrict__ oh, f16* __restrict__ ol, int ldo, float scale,
    const float* __restrict__ sav, const float* __restrict__ sbv) {
  f16* smem = (f16*)dsm;
  f16* tAh = smem;
  f16* tBh = smem + 8192;
  f16* tAl = smem + 16384;
  f16* tBl = smem + 24576;

  const int tid = threadIdx.x;
  const int lane = tid & 63, wid = tid >> 6;
  const int wr = wid >> 1, wc = wid & 1;
  const int brow = blockIdx.x * 128, bcol = blockIdx.y * 128;
  const int ar = lane & 15, k0 = (lane >> 4) * 8;
  const int crow = lane >> 3, ccol = (lane & 7) * 8;

  f32x4 acc[4][4] = {};
  const size_t aoff = (size_t)crow * K + ccol;

  for (int kt = 0; kt < K; kt += 64) {
    const f16* Ab = A + (size_t)brow * K + kt;
    const f16* Bb = B + (size_t)bcol * K + kt;
#pragma unroll
    for (int cc = 0; cc < 4; ++cc) {
      const int c = wid * 4 + cc;
      const size_t co = (size_t)c * 8 * K + aoff;
      gload16(Ab + co, tAh + c * 512);
      gload16(Bb + co, tBh + c * 512);
      if constexpr (NM >= 2) gload16(Al + (size_t)brow * K + kt + co, tAl + c * 512);
      if constexpr (NM == 3) gload16(Bl + (size_t)bcol * K + kt + co, tBl + c * 512);
    }
    __syncthreads();
#pragma unroll
    for (int ks = 0; ks < 2; ++ks) {
      f16x8 ah[4], bh[4], alv[4], blv[4];
#pragma unroll
      for (int m = 0; m < 4; ++m) {
        ah[m] = *(const f16x8*)&tAh[(wr * 64 + m * 16 + ar) * 64 + ks * 32 + k0];
        bh[m] = *(const f16x8*)&tBh[(wc * 64 + m * 16 + ar) * 64 + ks * 32 + k0];
        if constexpr (NM >= 2)
          alv[m] = *(const f16x8*)&tAl[(wr * 64 + m * 16 + ar) * 64 + ks * 32 + k0];
        if constexpr (NM == 3)
          blv[m] = *(const f16x8*)&tBl[(wc * 64 + m * 16 + ar) * 64 + ks * 32 + k0];
      }
#pragma unroll
      for (int m = 0; m < 4; ++m)
#pragma unroll
        for (int n = 0; n < 4; ++n) {
          acc[m][n] = __builtin_amdgcn_mfma_f32_16x16x32_f16(ah[m], bh[n], acc[m][n], 0, 0, 0);
          if constexpr (NM >= 2)
            acc[m][n] = __builtin_amdgcn_mfma_f32_16x16x32_f16(alv[m], bh[n], acc[m][n], 0, 0, 0);
          if constexpr (NM == 3)
            acc[m][n] = __builtin_amdgcn_mfma_f32_16x16x32_f16(ah[m], blv[n], acc[m][n], 0, 0, 0);
        }
    }
    __syncthreads();
  }

#pragma unroll
  for (int m = 0; m < 4; ++m)
#pragma unroll
    for (int n = 0; n < 4; ++n)
#pragma unroll
      for (int j = 0; j < 4; ++j) {
        const int row = brow + wr * 64 + m * 16 + (lane >> 4) * 4 + j;
        const int col = bcol + wc * 64 + n * 16 + ar;
        const size_t idx = (size_t)row * ldo + col;
        if constexpr (OUT == 1) {
          f16 h, l;
          split_f32(acc[m][n][j] * scale, h, l);
          oh[idx] = h;
          ol[idx] = l;
        } else {  // OUT == 4: rank1-subtract, h only
          const float v =
              (acc[m][n][j] - 256.0f - 0.5f * sav[col] - 0.5f * sbv[row]) * scale;
          oh[idx] = (f16)v;
        }
      }
}

extern "C" void kernel_launch(void* const* d_in, const int* in_sizes, int n_in,
                              void* d_out, int out_size, void* d_ws,
                              size_t ws_size, hipStream_t stream) {
  const float* x = (const float*)d_in[0];
  const float* Wq = (const float*)d_in[1];
  const float* Wk = (const float*)d_in[2];
  const float* Wv = (const float*)d_in[3];
  float* out = (float*)d_out;
  char* ws = (char*)d_ws;
  const size_t MiB = 1u << 20;
  f16* xh = (f16*)(ws + 0 * MiB);
  f16* xl = (f16*)(ws + 8 * MiB);
  f16* Th = (f16*)(ws + 16 * MiB);
  f16* Tl = (f16*)(ws + 24 * MiB);
  f16* Vt = (f16*)(ws + 32 * MiB);
  f16* Pt = (f16*)(ws + 40 * MiB);         // 32 MiB
  float* mtile = (float*)(ws + 72 * MiB);  // 256 KiB
  float* tsum = (float*)(ws + 73 * MiB);   // 256 KiB
  f16* Wqh = (f16*)(ws + 40 * MiB);        // dead-Pt temps (pre-k_qkt)
  f16* Wql = (f16*)(ws + 42 * MiB);
  f16* Wkh = (f16*)(ws + 44 * MiB);
  f16* Wkl = (f16*)(ws + 46 * MiB);
  f16* Mth = (f16*)(ws + 48 * MiB);
  f16* Wtvh = (f16*)(ws + 52 * MiB);
  float* sa = (float*)(ws + 54 * MiB);
  float* sb = (float*)(ws + 54 * MiB + 65536);
  float* rv = (float*)(ws + 8 * MiB);
  float* pv = (float*)(ws + 8 * MiB + 65536);
  float* qv = (float*)(ws + 8 * MiB + 131072);

  (void)hipFuncSetAttribute((const void*)k_qkt,
                            hipFuncAttributeMaxDynamicSharedMemorySize, 98304);
  (void)hipFuncSetAttribute((const void*)k_pvs,
                            hipFuncAttributeMaxDynamicSharedMemorySize, 73728);
  (void)hipFuncSetAttribute((const void*)pipe_bt<1024, 32>,
                            hipFuncAttributeMaxDynamicSharedMemorySize, 65536);

  k_split<<<dim3(1024, 1, 3), 256, 0, stream>>>(x, Wq, Wk, xh, xl, Wqh, Wql,
                                                Wkh, Wkl);
  k_wsplit_v<<<dim3(16, 16), 256, 0, stream>>>(Wv, Wtvh);
  k_rowsums<<<dim3(256, 2), 256, 0, stream>>>(Wq, Wk, sa, sb);
  gemm_bt<3, 4><<<dim3(8, 8), 256, 65536, stream>>>(
      Wkh, Wkl, Wqh, Wql, 1024, Mth, nullptr, 1024, 0.03125f, sa, sb);
  gemm_bt<2, 1><<<dim3(32, 8), 256, 49152, stream>>>(
      xh, xl, Mth, nullptr, 1024, Th, Tl, 1024, 1.0f, nullptr, nullptr);
  pipe_bt<1024, 32><<<dim3(256), 512, 65536, stream>>>(Wtvh, xh, Vt, 4096);
  k_rpq<<<dim3(1024), 256, 0, stream>>>(x, sa, sb, rv, pv, qv);
  k_qkt<<<dim3(256), 512, 98304, stream>>>(Th, Tl, xh, rv, pv, qv, Pt, mtile,
                                           tsum);
  k_pvs<<<dim3(256), 512, 73728, stream>>>(Pt, Vt, mtile, tsum, out);
}